// Round 5
// baseline (292.418 us; speedup 1.0000x reference)
//
#include <hip/hip_runtime.h>

#define DIMM 1024
#define NHEADS 16
#define HDIM 64
#define WIN 1024
#define GATEIN 20
#define BB 2
#define TT 2048
#define MTOT (BB*TT)   // 4096

typedef __attribute__((ext_vector_type(8))) short short8;
typedef __attribute__((ext_vector_type(4))) float f32x4;
typedef __attribute__((ext_vector_type(16))) float f32x16;
typedef const __attribute__((address_space(1))) void gvoid_t;
typedef __attribute__((address_space(3))) void lvoid_t;

__device__ __forceinline__ unsigned short f2b(float f) {
  union { float f; unsigned u; } c; c.f = f;
  unsigned u = c.u + 0x7fffu + ((c.u >> 16) & 1u);
  return (unsigned short)(u >> 16);
}
__device__ __forceinline__ float b2f(unsigned short s) {
  union { unsigned u; float f; } c; c.u = ((unsigned)s) << 16;
  return c.f;
}
__device__ __forceinline__ unsigned cvt_pk_bf16(float lo, float hi) {
  unsigned r;
  asm("v_cvt_pk_bf16_f32 %0, %1, %2" : "=v"(r) : "v"(lo), "v"(hi));
  return r;
}
// cross-half (lane ^ 32) reductions via permlane32_swap (VALU, no DS)
__device__ __forceinline__ float xmax32(float x) {
  union { float f; unsigned u; } c; c.f = x;
  auto pr = __builtin_amdgcn_permlane32_swap(c.u, c.u, false, false);
  union { unsigned u; float f; } a, b; a.u = pr[0]; b.u = pr[1];
  return fmaxf(a.f, b.f);
}
__device__ __forceinline__ float xsum32(float x) {
  union { float f; unsigned u; } c; c.f = x;
  auto pr = __builtin_amdgcn_permlane32_swap(c.u, c.u, false, false);
  union { unsigned u; float f; } a, b; a.u = pr[0]; b.u = pr[1];
  return a.f + b.f;
}

// ---------------- conversion f32 -> bf16 (4 elems/thread) ----------------
__global__ void cvt_bf16_kernel(const float* __restrict__ src,
                                unsigned short* __restrict__ dst, int n4) {
  int i = blockIdx.x * blockDim.x + threadIdx.x;
  if (i >= n4) return;
  float4 v = ((const float4*)src)[i];
  union { unsigned short s[4]; uint2 u; } o;
  o.s[0] = f2b(v.x); o.s[1] = f2b(v.y); o.s[2] = f2b(v.z); o.s[3] = f2b(v.w);
  *(uint2*)(dst + (size_t)i * 4) = o.u;
}

// ---------------- bias concat [bq|bk|bv] -> 3072 ----------------
__global__ void bias_cat_kernel(const float* __restrict__ bq, const float* __restrict__ bk,
                                const float* __restrict__ bv, float* __restrict__ out) {
  int i = blockIdx.x * blockDim.x + threadIdx.x;
  if (i >= 3072) return;
  out[i] = (i < 1024) ? bq[i] : (i < 2048) ? bk[i - 1024] : bv[i - 2048];
}

// ---------------- gate = sigmoid(x[:, :20] @ Wg^T + bg), [M][H] f32 ----------------
__global__ void gate_kernel(const float* __restrict__ x, const float* __restrict__ Wg,
                            const float* __restrict__ bg, float* __restrict__ gate) {
  int i = blockIdx.x * blockDim.x + threadIdx.x;   // M*H
  if (i >= MTOT * NHEADS) return;
  int h = i & 15;
  int m = i >> 4;
  const float* xr = x + (size_t)m * DIMM;
  const float* wr = Wg + h * GATEIN;
  float z = bg[h];
#pragma unroll
  for (int g = 0; g < GATEIN; ++g) z += xr[g] * wr[g];
  gate[i] = 1.f / (1.f + __expf(-z));
}

// ---------------- GEMM: C[M,N] = A[M,K] @ Bw[N,K]^T + bias, bf16 in, f32 acc ----------------
template<int OUTBF>
__global__ __launch_bounds__(256) void gemm_bt(const unsigned short* __restrict__ A,
                                               const unsigned short* __restrict__ Bw,
                                               const float* __restrict__ bias,
                                               void* __restrict__ Cout,
                                               int M, int N, int K) {
  __shared__ __align__(16) unsigned short As[128 * 32];
  __shared__ __align__(16) unsigned short Bs[128 * 32];
  const int tid = threadIdx.x;
  const int lane = tid & 63, wid = tid >> 6;
  const int g = lane >> 4, r16 = lane & 15;
  const int m0 = blockIdx.y * 128, n0 = blockIdx.x * 128;
  const int wr = (wid >> 1) * 64, wc = (wid & 1) * 64;
  const int wbase = wid * 64;

  f32x4 acc[4][4];
#pragma unroll
  for (int i = 0; i < 4; ++i)
#pragma unroll
    for (int j = 0; j < 4; ++j) acc[i][j] = (f32x4){0.f, 0.f, 0.f, 0.f};

  for (int k0 = 0; k0 < K; k0 += 32) {
#pragma unroll
    for (int j = 0; j < 2; ++j) {
      int sbase = j * 256 + wbase;
      int s = sbase + lane;
      const unsigned short* gA = A + (size_t)(m0 + (s >> 2)) * K + k0 + (s & 3) * 8;
      __builtin_amdgcn_global_load_lds((gvoid_t*)gA, (lvoid_t*)((char*)As + sbase * 16), 16, 0, 0);
      const unsigned short* gB = Bw + (size_t)(n0 + (s >> 2)) * K + k0 + (s & 3) * 8;
      __builtin_amdgcn_global_load_lds((gvoid_t*)gB, (lvoid_t*)((char*)Bs + sbase * 16), 16, 0, 0);
    }
    __syncthreads();
    short8 af[4], bf[4];
#pragma unroll
    for (int mf = 0; mf < 4; ++mf)
      af[mf] = *(const short8*)(As + (wr + mf * 16 + r16) * 32 + g * 8);
#pragma unroll
    for (int nf = 0; nf < 4; ++nf)
      bf[nf] = *(const short8*)(Bs + (wc + nf * 16 + r16) * 32 + g * 8);
#pragma unroll
    for (int mf = 0; mf < 4; ++mf)
#pragma unroll
      for (int nf = 0; nf < 4; ++nf)
        acc[mf][nf] = __builtin_amdgcn_mfma_f32_16x16x32_bf16(af[mf], bf[nf], acc[mf][nf], 0, 0, 0);
    __syncthreads();
  }
#pragma unroll
  for (int mf = 0; mf < 4; ++mf)
#pragma unroll
    for (int nf = 0; nf < 4; ++nf)
#pragma unroll
      for (int rr = 0; rr < 4; ++rr) {
        int m = m0 + wr + mf * 16 + g * 4 + rr;
        int n = n0 + wc + nf * 16 + r16;
        float v = acc[mf][nf][rr] + bias[n];
        if (OUTBF) ((unsigned short*)Cout)[(size_t)m * N + n] = f2b(v);
        else       ((float*)Cout)[(size_t)m * N + n] = v;
      }
}

// ---------------- RoPE + relayout: qkv_cat [M][3072] -> q_r/k_r [B*H][T][64] ----------------
// q is scaled by 0.125 * log2(e): attention scores come out in log2 domain.
#define QSCALE (0.125f * 1.4426950408889634f)
__global__ void rope_kernel(const unsigned short* __restrict__ qkv,
                            const float* __restrict__ cosb, const float* __restrict__ sinb,
                            unsigned short* __restrict__ qr, unsigned short* __restrict__ kr) {
  int i = blockIdx.x * blockDim.x + threadIdx.x;   // M*H*32
  if (i >= MTOT * NHEADS * 32) return;
  int d = i & 31;
  int h = (i >> 5) & 15;
  int m = i >> 9;             // b*T + t
  int t = m & (TT - 1);
  int b = m >> 11;
  const unsigned short* row = qkv + (size_t)m * 3072;
  float c = cosb[t * 32 + d], s = sinb[t * 32 + d];
  float q1 = b2f(row[h * 64 + d]),        q2 = b2f(row[h * 64 + d + 32]);
  float k1 = b2f(row[1024 + h * 64 + d]), k2 = b2f(row[1024 + h * 64 + d + 32]);
  size_t o = ((size_t)(b * NHEADS + h) * TT + t) * HDIM + d;
  qr[o]      = f2b((q1 * c - q2 * s) * QSCALE);
  qr[o + 32] = f2b((q1 * s + q2 * c) * QSCALE);
  kr[o]      = f2b(k1 * c - k2 * s);
  kr[o + 32] = f2b(k1 * s + k2 * c);
}

// ---------------- V transpose: qkv[:,2048:3072] -> vt [B*H][64 d][2048 t] ----------------
__global__ __launch_bounds__(256) void vtrans_kernel(const unsigned short* __restrict__ qkv,
                                                     unsigned short* __restrict__ vt) {
  __shared__ unsigned short tile[64][66];
  const int t0 = blockIdx.x * 64;
  const int bh = blockIdx.y;
  const int b = bh >> 4, h = bh & 15;
  const int tid = threadIdx.x;
  const int r = tid >> 2;
  const int c0 = (tid & 3) * 16;
  {
    const unsigned short* src = qkv + (size_t)(b * TT + t0 + r) * 3072 + 2048 + h * 64 + c0;
    short8 v0 = *(const short8*)src;
    short8 v1 = *(const short8*)(src + 8);
#pragma unroll
    for (int j = 0; j < 8; ++j) {
      tile[r][c0 + j] = (unsigned short)v0[j];
      tile[r][c0 + 8 + j] = (unsigned short)v1[j];
    }
  }
  __syncthreads();
  {
    const int d = tid >> 2;
    const int tc = (tid & 3) * 16;
    short8 o0, o1;
#pragma unroll
    for (int j = 0; j < 8; ++j) {
      o0[j] = (short)tile[tc + j][d];
      o1[j] = (short)tile[tc + 8 + j][d];
    }
    unsigned short* dst = vt + ((size_t)bh * HDIM + d) * TT + t0 + tc;
    *(short8*)dst = o0;
    *(short8*)(dst + 8) = o1;
  }
}

// ---------------- flash attention: 4-way split-KV, swapped QK^T (32x32) ----------------
// Block = (bh, q-tile of 32 rows), 4 waves. Wave w takes KV steps w, w+4, w+8,...
// Each wave: lane-local online softmax (exp2 domain, defer-max THR=8).
// Combine via LDS: m*,l* from per-wave (m,l); waves 1-3 write scaled O; wave 0 sums+stores.
__global__ __launch_bounds__(256, 5) void attn_kernel(const unsigned short* __restrict__ qr,
                                                      const unsigned short* __restrict__ kr,
                                                      const unsigned short* __restrict__ vt,
                                                      const float* __restrict__ gate,
                                                      unsigned short* __restrict__ attn_out) {
  __shared__ float lds_m[4][32];
  __shared__ float lds_l[4][32];
  __shared__ float lds_O[3][64][33];   // (lane+r)%32 banks -> 2-way (free)
  const int tid = threadIdx.x;
  const int lane = tid & 63, wid = tid >> 6;
  const int l31 = lane & 31, hi = lane >> 5;

  // XCD swizzle: 2048 blocks; each XCD owns 4 bh (Q+K+V ~3MB < 4MB L2)
  const int fid = blockIdx.x;
  const int idx = fid >> 3;                 // 0..255
  const int bh = (fid & 7) * 4 + (idx >> 6);
  const int q0 = (idx & 63) * 32;
  const int b = bh >> 4, h = bh & 15;
  const unsigned short* kptr = kr + (size_t)bh * TT * HDIM;
  const unsigned short* vptr = vt + (size_t)bh * HDIM * TT;
  const int q = q0 + l31;                   // this lane's q row

  // Q B-frags (col=q, k(d) = st*16 + hi*8 + j)
  short8 qf[4];
#pragma unroll
  for (int st = 0; st < 4; ++st)
    qf[st] = *(const short8*)(qr + (size_t)bh * TT * HDIM + (size_t)q * HDIM + st * 16 + hi * 8);

  f32x16 SZERO;
#pragma unroll
  for (int r = 0; r < 16; ++r) SZERO[r] = 0.f;
  f32x16 o0 = SZERO, o1 = SZERO;
  float mrun = -1e30f, lrun = 0.f;

  int kv_lo = q0 - WIN;
  if (kv_lo < 0) kv_lo = 0;
  const int kv_hi = q0 + 32;

  // step body: S from kcur, prefetch K(+128) into knext, V loads, softmax, PV
  auto doStep = [&](int kv, short8 (&kcur)[4], short8 (&knext)[4]) {
    f32x16 s;
    s = __builtin_amdgcn_mfma_f32_32x32x16_bf16(kcur[0], qf[0], SZERO, 0, 0, 0);
    s = __builtin_amdgcn_mfma_f32_32x32x16_bf16(kcur[1], qf[1], s, 0, 0, 0);
    s = __builtin_amdgcn_mfma_f32_32x32x16_bf16(kcur[2], qf[2], s, 0, 0, 0);
    s = __builtin_amdgcn_mfma_f32_32x32x16_bf16(kcur[3], qf[3], s, 0, 0, 0);

    const int kvn = (kv + 128 < kv_hi) ? kv + 128 : kv;
    const unsigned short* krow = kptr + (size_t)(kvn + l31) * HDIM + hi * 8;
    knext[0] = *(const short8*)(krow);
    knext[1] = *(const short8*)(krow + 16);
    knext[2] = *(const short8*)(krow + 32);
    knext[3] = *(const short8*)(krow + 48);

    const unsigned short* vrow = vptr + (size_t)l31 * TT + kv + hi * 8;
    short8 vf00 = *(const short8*)(vrow);
    short8 vf01 = *(const short8*)(vrow + 16);
    short8 vf10 = *(const short8*)(vrow + 32 * TT);
    short8 vf11 = *(const short8*)(vrow + 32 * TT + 16);

    // masks only on peeled steps (wave-uniform branches)
    float sv[16];
    if (kv == q0) {            // causal (global last step)
#pragma unroll
      for (int r = 0; r < 16; ++r) {
        int key = kv + (r & 3) + 8 * (r >> 2) + 4 * hi;
        sv[r] = (key <= q) ? s[r] : -1e30f;
      }
    } else if (q0 >= WIN && kv == kv_lo) {   // window edge (global first step)
#pragma unroll
      for (int r = 0; r < 16; ++r) {
        int key = kv + (r & 3) + 8 * (r >> 2) + 4 * hi;
        sv[r] = (key + WIN >= q) ? s[r] : -1e30f;
      }
    } else {
#pragma unroll
      for (int r = 0; r < 16; ++r) sv[r] = s[r];
    }

    float a0 = fmaxf(sv[0], sv[1]),   a1 = fmaxf(sv[2], sv[3]);
    float a2 = fmaxf(sv[4], sv[5]),   a3 = fmaxf(sv[6], sv[7]);
    float a4 = fmaxf(sv[8], sv[9]),   a5 = fmaxf(sv[10], sv[11]);
    float a6 = fmaxf(sv[12], sv[13]), a7 = fmaxf(sv[14], sv[15]);
    float b0 = fmaxf(a0, a1), b1 = fmaxf(a2, a3), b2 = fmaxf(a4, a5), b3 = fmaxf(a6, a7);
    float lm = fmaxf(fmaxf(b0, b1), fmaxf(b2, b3));
    lm = xmax32(lm);

    if (!__all(lm - mrun <= 8.f)) {
      float mnew = fmaxf(mrun, lm);
      float scf = __builtin_exp2f(mrun - mnew);
      mrun = mnew;
      lrun *= scf;
#pragma unroll
      for (int r = 0; r < 16; ++r) { o0[r] *= scf; o1[r] *= scf; }
    }

    float pv[16];
#pragma unroll
    for (int r = 0; r < 16; ++r) pv[r] = __builtin_exp2f(sv[r] - mrun);
    float c0 = (pv[0] + pv[1]) + (pv[2] + pv[3]);
    float c1 = (pv[4] + pv[5]) + (pv[6] + pv[7]);
    float c2 = (pv[8] + pv[9]) + (pv[10] + pv[11]);
    float c3 = (pv[12] + pv[13]) + (pv[14] + pv[15]);
    lrun += xsum32((c0 + c1) + (c2 + c3));

    unsigned w0 = cvt_pk_bf16(pv[0],  pv[1]),  w1 = cvt_pk_bf16(pv[2],  pv[3]);
    unsigned w2 = cvt_pk_bf16(pv[4],  pv[5]),  w3 = cvt_pk_bf16(pv[6],  pv[7]);
    unsigned w4 = cvt_pk_bf16(pv[8],  pv[9]),  w5 = cvt_pk_bf16(pv[10], pv[11]);
    unsigned w6 = cvt_pk_bf16(pv[12], pv[13]), w7 = cvt_pk_bf16(pv[14], pv[15]);
    auto s1 = __builtin_amdgcn_permlane32_swap(w0, w2, false, false);
    auto s2 = __builtin_amdgcn_permlane32_swap(w1, w3, false, false);
    auto s3 = __builtin_amdgcn_permlane32_swap(w4, w6, false, false);
    auto s4 = __builtin_amdgcn_permlane32_swap(w5, w7, false, false);
    union { unsigned u[4]; short8 s8; } pf0, pf1;
    pf0.u[0] = s1[0]; pf0.u[1] = s2[0]; pf0.u[2] = s1[1]; pf0.u[3] = s2[1];
    pf1.u[0] = s3[0]; pf1.u[1] = s4[0]; pf1.u[2] = s3[1]; pf1.u[3] = s4[1];

    o0 = __builtin_amdgcn_mfma_f32_32x32x16_bf16(vf00, pf0.s8, o0, 0, 0, 0);
    o1 = __builtin_amdgcn_mfma_f32_32x32x16_bf16(vf10, pf0.s8, o1, 0, 0, 0);
    o0 = __builtin_amdgcn_mfma_f32_32x32x16_bf16(vf01, pf1.s8, o0, 0, 0, 0);
    o1 = __builtin_amdgcn_mfma_f32_32x32x16_bf16(vf11, pf1.s8, o1, 0, 0, 0);
  };

  // wave wid: steps kv_lo + (wid + 4i)*32
  const int kv0 = kv_lo + wid * 32;
  if (kv0 < kv_hi) {
    short8 kA[4], kB[4];
    {
      const unsigned short* krow = kptr + (size_t)(kv0 + l31) * HDIM + hi * 8;
      kA[0] = *(const short8*)(krow);
      kA[1] = *(const short8*)(krow + 16);
      kA[2] = *(const short8*)(krow + 32);
      kA[3] = *(const short8*)(krow + 48);
    }
    for (int kv = kv0; ; ) {
      doStep(kv, kA, kB);
      kv += 128; if (kv >= kv_hi) break;
      doStep(kv, kB, kA);
      kv += 128; if (kv >= kv_hi) break;
    }
  }

  // ---- combine across the 4 waves ----
  if (hi == 0) { lds_m[wid][l31] = mrun; lds_l[wid][l31] = lrun; }
  __syncthreads();
  float m0 = lds_m[0][l31], m1 = lds_m[1][l31], m2 = lds_m[2][l31], m3 = lds_m[3][l31];
  float mstar = fmaxf(fmaxf(m0, m1), fmaxf(m2, m3));
  float myscale = __builtin_exp2f(mrun - mstar);
  if (wid != 0) {
#pragma unroll
    for (int r = 0; r < 16; ++r) {
      lds_O[wid - 1][lane][r]      = o0[r] * myscale;
      lds_O[wid - 1][lane][16 + r] = o1[r] * myscale;
    }
  }
  __syncthreads();
  if (wid == 0) {
    float lstar = __builtin_exp2f(m0 - mstar) * lds_l[0][l31]
                + __builtin_exp2f(m1 - mstar) * lds_l[1][l31]
                + __builtin_exp2f(m2 - mstar) * lds_l[2][l31]
                + __builtin_exp2f(m3 - mstar) * lds_l[3][l31];
    float gv = gate[((size_t)b * TT + q) * NHEADS + h];
    float inv = gv / lstar;
    float of0[16], of1[16];
#pragma unroll
    for (int r = 0; r < 16; ++r) {
      of0[r] = o0[r] * myscale + lds_O[0][lane][r]      + lds_O[1][lane][r]      + lds_O[2][lane][r];
      of1[r] = o1[r] * myscale + lds_O[0][lane][16 + r] + lds_O[1][lane][16 + r] + lds_O[2][lane][16 + r];
    }
    unsigned short* orow = attn_out + ((size_t)b * TT + q) * DIMM + h * HDIM;
#pragma unroll
    for (int a2 = 0; a2 < 4; ++a2) {
      int d0 = a2 * 8 + hi * 4;
      union { unsigned short s[4]; uint2 u; } x0, x1;
#pragma unroll
      for (int c = 0; c < 4; ++c) {
        x0.s[c] = f2b(of0[a2 * 4 + c] * inv);
        x1.s[c] = f2b(of1[a2 * 4 + c] * inv);
      }
      *(uint2*)(orow + d0) = x0.u;
      *(uint2*)(orow + 32 + d0) = x1.u;
    }
  }
}

// ---------------- workspace layout (bytes) ----------------
#define OFF_XB    ((size_t)0)
#define OFF_WQKV  ((size_t)8388608)
#define OFF_WO    ((size_t)14680064)
#define OFF_BCAT  ((size_t)16777216)
#define OFF_QKV   ((size_t)16793600)
#define OFF_QR    ((size_t)41959424)
#define OFF_KR    ((size_t)50348032)
#define OFF_VT    ((size_t)58736640)
#define OFF_ATTN  ((size_t)67125248)
#define OFF_GATE  ((size_t)75513856)

extern "C" void kernel_launch(void* const* d_in, const int* in_sizes, int n_in,
                              void* d_out, int out_size, void* d_ws, size_t ws_size,
                              hipStream_t stream) {
  const float* x    = (const float*)d_in[0];
  const float* Wq   = (const float*)d_in[1];
  const float* bq   = (const float*)d_in[2];
  const float* Wk   = (const float*)d_in[3];
  const float* bk   = (const float*)d_in[4];
  const float* Wv   = (const float*)d_in[5];
  const float* bv   = (const float*)d_in[6];
  const float* Wo   = (const float*)d_in[7];
  const float* bo   = (const float*)d_in[8];
  const float* Wg   = (const float*)d_in[9];
  const float* bg   = (const float*)d_in[10];
  const float* cosb = (const float*)d_in[11];
  const float* sinb = (const float*)d_in[12];
  float* out = (float*)d_out;
  char* ws = (char*)d_ws;

  unsigned short* xb    = (unsigned short*)(ws + OFF_XB);
  unsigned short* wqkv  = (unsigned short*)(ws + OFF_WQKV);
  unsigned short* wob   = (unsigned short*)(ws + OFF_WO);
  float*          bcat  = (float*)(ws + OFF_BCAT);
  unsigned short* qkv   = (unsigned short*)(ws + OFF_QKV);
  unsigned short* q_r   = (unsigned short*)(ws + OFF_QR);
  unsigned short* k_r   = (unsigned short*)(ws + OFF_KR);
  unsigned short* v_t   = (unsigned short*)(ws + OFF_VT);
  unsigned short* attn  = (unsigned short*)(ws + OFF_ATTN);
  float*          gateb = (float*)(ws + OFF_GATE);

  cvt_bf16_kernel<<<4096, 256, 0, stream>>>(x, xb, 4194304 / 4);
  cvt_bf16_kernel<<<1024, 256, 0, stream>>>(Wq, wqkv,            1048576 / 4);
  cvt_bf16_kernel<<<1024, 256, 0, stream>>>(Wk, wqkv + 1048576,  1048576 / 4);
  cvt_bf16_kernel<<<1024, 256, 0, stream>>>(Wv, wqkv + 2097152,  1048576 / 4);
  cvt_bf16_kernel<<<1024, 256, 0, stream>>>(Wo, wob,             1048576 / 4);
  bias_cat_kernel<<<12, 256, 0, stream>>>(bq, bk, bv, bcat);
  gate_kernel<<<256, 256, 0, stream>>>(x, Wg, bg, gateb);

  // fused QKV projection: [4096,1024] @ [3072,1024]^T
  gemm_bt<1><<<dim3(24, 32), 256, 0, stream>>>(xb, wqkv, bcat, qkv, MTOT, 3072, 1024);

  // RoPE (q scaled by 0.125*log2e) + V transpose
  rope_kernel<<<8192, 256, 0, stream>>>(qkv, cosb, sinb, q_r, k_r);
  vtrans_kernel<<<dim3(32, 32), 256, 0, stream>>>(qkv, v_t);

  // windowed causal flash attention + gate (4-way split-KV, LDS combine)
  attn_kernel<<<2048, 256, 0, stream>>>(q_r, k_r, v_t, gateb, attn);

  // output projection: [4096,1024] @ [1024,1024]^T + bo -> f32 out
  gemm_bt<0><<<dim3(8, 32), 256, 0, stream>>>(attn, wob, bo, out, MTOT, 1024, 1024);
}

// Round 6
// 159.714 us; speedup vs baseline: 1.8309x; 1.8309x over previous
//
#include <hip/hip_runtime.h>

#define DIMM 1024
#define NHEADS 16
#define HDIM 64
#define WIN 1024
#define GATEIN 20
#define BB 2
#define TT 2048
#define MTOT (BB*TT)   // 4096

typedef __attribute__((ext_vector_type(8))) short short8;
typedef __attribute__((ext_vector_type(4))) float f32x4;
typedef __attribute__((ext_vector_type(16))) float f32x16;
typedef const __attribute__((address_space(1))) void gvoid_t;
typedef __attribute__((address_space(3))) void lvoid_t;

__device__ __forceinline__ unsigned short f2b(float f) {
  union { float f; unsigned u; } c; c.f = f;
  unsigned u = c.u + 0x7fffu + ((c.u >> 16) & 1u);
  return (unsigned short)(u >> 16);
}
__device__ __forceinline__ float b2f(unsigned short s) {
  union { unsigned u; float f; } c; c.u = ((unsigned)s) << 16;
  return c.f;
}
__device__ __forceinline__ unsigned cvt_pk_bf16(float lo, float hi) {
  unsigned r;
  asm("v_cvt_pk_bf16_f32 %0, %1, %2" : "=v"(r) : "v"(lo), "v"(hi));
  return r;
}
// cross-half (lane ^ 32) reductions via permlane32_swap (VALU, no DS)
__device__ __forceinline__ float xmax32(float x) {
  union { float f; unsigned u; } c; c.f = x;
  auto pr = __builtin_amdgcn_permlane32_swap(c.u, c.u, false, false);
  union { unsigned u; float f; } a, b; a.u = pr[0]; b.u = pr[1];
  return fmaxf(a.f, b.f);
}
__device__ __forceinline__ float xsum32(float x) {
  union { float f; unsigned u; } c; c.f = x;
  auto pr = __builtin_amdgcn_permlane32_swap(c.u, c.u, false, false);
  union { unsigned u; float f; } a, b; a.u = pr[0]; b.u = pr[1];
  return a.f + b.f;
}

// ---------------- conversion f32 -> bf16 (4 elems/thread) ----------------
__global__ void cvt_bf16_kernel(const float* __restrict__ src,
                                unsigned short* __restrict__ dst, int n4) {
  int i = blockIdx.x * blockDim.x + threadIdx.x;
  if (i >= n4) return;
  float4 v = ((const float4*)src)[i];
  union { unsigned short s[4]; uint2 u; } o;
  o.s[0] = f2b(v.x); o.s[1] = f2b(v.y); o.s[2] = f2b(v.z); o.s[3] = f2b(v.w);
  *(uint2*)(dst + (size_t)i * 4) = o.u;
}

// ---------------- bias concat [bq|bk|bv] -> 3072 ----------------
__global__ void bias_cat_kernel(const float* __restrict__ bq, const float* __restrict__ bk,
                                const float* __restrict__ bv, float* __restrict__ out) {
  int i = blockIdx.x * blockDim.x + threadIdx.x;
  if (i >= 3072) return;
  out[i] = (i < 1024) ? bq[i] : (i < 2048) ? bk[i - 1024] : bv[i - 2048];
}

// ---------------- gate = sigmoid(x[:, :20] @ Wg^T + bg), [M][H] f32 ----------------
__global__ void gate_kernel(const float* __restrict__ x, const float* __restrict__ Wg,
                            const float* __restrict__ bg, float* __restrict__ gate) {
  int i = blockIdx.x * blockDim.x + threadIdx.x;   // M*H
  if (i >= MTOT * NHEADS) return;
  int h = i & 15;
  int m = i >> 4;
  const float* xr = x + (size_t)m * DIMM;
  const float* wr = Wg + h * GATEIN;
  float z = bg[h];
#pragma unroll
  for (int g = 0; g < GATEIN; ++g) z += xr[g] * wr[g];
  gate[i] = 1.f / (1.f + __expf(-z));
}

// ---------------- GEMM: C[M,N] = A[M,K] @ Bw[N,K]^T + bias, bf16 in, f32 acc ----------------
template<int OUTBF>
__global__ __launch_bounds__(256) void gemm_bt(const unsigned short* __restrict__ A,
                                               const unsigned short* __restrict__ Bw,
                                               const float* __restrict__ bias,
                                               void* __restrict__ Cout,
                                               int M, int N, int K) {
  __shared__ __align__(16) unsigned short As[128 * 32];
  __shared__ __align__(16) unsigned short Bs[128 * 32];
  const int tid = threadIdx.x;
  const int lane = tid & 63, wid = tid >> 6;
  const int g = lane >> 4, r16 = lane & 15;
  const int m0 = blockIdx.y * 128, n0 = blockIdx.x * 128;
  const int wr = (wid >> 1) * 64, wc = (wid & 1) * 64;
  const int wbase = wid * 64;

  f32x4 acc[4][4];
#pragma unroll
  for (int i = 0; i < 4; ++i)
#pragma unroll
    for (int j = 0; j < 4; ++j) acc[i][j] = (f32x4){0.f, 0.f, 0.f, 0.f};

  for (int k0 = 0; k0 < K; k0 += 32) {
#pragma unroll
    for (int j = 0; j < 2; ++j) {
      int sbase = j * 256 + wbase;
      int s = sbase + lane;
      const unsigned short* gA = A + (size_t)(m0 + (s >> 2)) * K + k0 + (s & 3) * 8;
      __builtin_amdgcn_global_load_lds((gvoid_t*)gA, (lvoid_t*)((char*)As + sbase * 16), 16, 0, 0);
      const unsigned short* gB = Bw + (size_t)(n0 + (s >> 2)) * K + k0 + (s & 3) * 8;
      __builtin_amdgcn_global_load_lds((gvoid_t*)gB, (lvoid_t*)((char*)Bs + sbase * 16), 16, 0, 0);
    }
    __syncthreads();
    short8 af[4], bf[4];
#pragma unroll
    for (int mf = 0; mf < 4; ++mf)
      af[mf] = *(const short8*)(As + (wr + mf * 16 + r16) * 32 + g * 8);
#pragma unroll
    for (int nf = 0; nf < 4; ++nf)
      bf[nf] = *(const short8*)(Bs + (wc + nf * 16 + r16) * 32 + g * 8);
#pragma unroll
    for (int mf = 0; mf < 4; ++mf)
#pragma unroll
      for (int nf = 0; nf < 4; ++nf)
        acc[mf][nf] = __builtin_amdgcn_mfma_f32_16x16x32_bf16(af[mf], bf[nf], acc[mf][nf], 0, 0, 0);
    __syncthreads();
  }
#pragma unroll
  for (int mf = 0; mf < 4; ++mf)
#pragma unroll
    for (int nf = 0; nf < 4; ++nf)
#pragma unroll
      for (int rr = 0; rr < 4; ++rr) {
        int m = m0 + wr + mf * 16 + g * 4 + rr;
        int n = n0 + wc + nf * 16 + r16;
        float v = acc[mf][nf][rr] + bias[n];
        if (OUTBF) ((unsigned short*)Cout)[(size_t)m * N + n] = f2b(v);
        else       ((float*)Cout)[(size_t)m * N + n] = v;
      }
}

// ---------------- RoPE + relayout: qkv_cat [M][3072] -> q_r/k_r [B*H][T][64] ----------------
// q is scaled by 0.125 * log2(e): attention scores come out in log2 domain.
#define QSCALE (0.125f * 1.4426950408889634f)
__global__ void rope_kernel(const unsigned short* __restrict__ qkv,
                            const float* __restrict__ cosb, const float* __restrict__ sinb,
                            unsigned short* __restrict__ qr, unsigned short* __restrict__ kr) {
  int i = blockIdx.x * blockDim.x + threadIdx.x;   // M*H*32
  if (i >= MTOT * NHEADS * 32) return;
  int d = i & 31;
  int h = (i >> 5) & 15;
  int m = i >> 9;             // b*T + t
  int t = m & (TT - 1);
  int b = m >> 11;
  const unsigned short* row = qkv + (size_t)m * 3072;
  float c = cosb[t * 32 + d], s = sinb[t * 32 + d];
  float q1 = b2f(row[h * 64 + d]),        q2 = b2f(row[h * 64 + d + 32]);
  float k1 = b2f(row[1024 + h * 64 + d]), k2 = b2f(row[1024 + h * 64 + d + 32]);
  size_t o = ((size_t)(b * NHEADS + h) * TT + t) * HDIM + d;
  qr[o]      = f2b((q1 * c - q2 * s) * QSCALE);
  qr[o + 32] = f2b((q1 * s + q2 * c) * QSCALE);
  kr[o]      = f2b(k1 * c - k2 * s);
  kr[o + 32] = f2b(k1 * s + k2 * c);
}

// ---------------- V transpose: qkv[:,2048:3072] -> vt [B*H][64 d][2048 t] ----------------
__global__ __launch_bounds__(256) void vtrans_kernel(const unsigned short* __restrict__ qkv,
                                                     unsigned short* __restrict__ vt) {
  __shared__ unsigned short tile[64][66];
  const int t0 = blockIdx.x * 64;
  const int bh = blockIdx.y;
  const int b = bh >> 4, h = bh & 15;
  const int tid = threadIdx.x;
  const int r = tid >> 2;
  const int c0 = (tid & 3) * 16;
  {
    const unsigned short* src = qkv + (size_t)(b * TT + t0 + r) * 3072 + 2048 + h * 64 + c0;
    short8 v0 = *(const short8*)src;
    short8 v1 = *(const short8*)(src + 8);
#pragma unroll
    for (int j = 0; j < 8; ++j) {
      tile[r][c0 + j] = (unsigned short)v0[j];
      tile[r][c0 + 8 + j] = (unsigned short)v1[j];
    }
  }
  __syncthreads();
  {
    const int d = tid >> 2;
    const int tc = (tid & 3) * 16;
    short8 o0, o1;
#pragma unroll
    for (int j = 0; j < 8; ++j) {
      o0[j] = (short)tile[tc + j][d];
      o1[j] = (short)tile[tc + 8 + j][d];
    }
    unsigned short* dst = vt + ((size_t)bh * HDIM + d) * TT + t0 + tc;
    *(short8*)dst = o0;
    *(short8*)(dst + 8) = o1;
  }
}

// ---------------- flash attention: 4-way split-KV, swapped QK^T (32x32) ----------------
// Block = (bh, q-tile of 32 rows), 4 waves. Wave w takes KV steps w, w+4, w+8,...
// Each wave: lane-local online softmax (exp2 domain, defer-max THR=8).
// Combine via LDS. NOTE: no min-waves bound — R4's (256,5) caused total spill (hbm 7.4e8).
__global__ __launch_bounds__(256) void attn_kernel(const unsigned short* __restrict__ qr,
                                                   const unsigned short* __restrict__ kr,
                                                   const unsigned short* __restrict__ vt,
                                                   const float* __restrict__ gate,
                                                   unsigned short* __restrict__ attn_out) {
  __shared__ float lds_m[4][32];
  __shared__ float lds_l[4][32];
  __shared__ float lds_O[3][64][33];   // (lane+r)%32 banks -> 2-way (free)
  const int tid = threadIdx.x;
  const int lane = tid & 63, wid = tid >> 6;
  const int l31 = lane & 31, hi = lane >> 5;

  // XCD swizzle: 2048 blocks; each XCD owns 4 bh (Q+K+V ~3MB < 4MB L2)
  const int fid = blockIdx.x;
  const int idx = fid >> 3;                 // 0..255
  const int bh = (fid & 7) * 4 + (idx >> 6);
  const int q0 = (idx & 63) * 32;
  const int b = bh >> 4, h = bh & 15;
  const unsigned short* kptr = kr + (size_t)bh * TT * HDIM;
  const unsigned short* vptr = vt + (size_t)bh * HDIM * TT;
  const int q = q0 + l31;                   // this lane's q row

  // Q B-frags (col=q, k(d) = st*16 + hi*8 + j)
  short8 qf[4];
#pragma unroll
  for (int st = 0; st < 4; ++st)
    qf[st] = *(const short8*)(qr + (size_t)bh * TT * HDIM + (size_t)q * HDIM + st * 16 + hi * 8);

  f32x16 o0, o1;
#pragma unroll
  for (int r = 0; r < 16; ++r) { o0[r] = 0.f; o1[r] = 0.f; }
  float mrun = -1e30f, lrun = 0.f;

  int kv_lo = q0 - WIN;
  if (kv_lo < 0) kv_lo = 0;
  const int kv_hi = q0 + 32;

  // wave wid handles steps kv_lo + (wid + 4i)*32
  for (int kv = kv_lo + wid * 32; kv < kv_hi; kv += 128) {
    // K fragments (L2-resident); V issued immediately after (independent of S)
    const unsigned short* krow = kptr + (size_t)(kv + l31) * HDIM + hi * 8;
    short8 k0 = *(const short8*)(krow);
    short8 k1 = *(const short8*)(krow + 16);
    short8 k2 = *(const short8*)(krow + 32);
    short8 k3 = *(const short8*)(krow + 48);
    const unsigned short* vrow = vptr + (size_t)l31 * TT + kv + hi * 8;
    short8 vf00 = *(const short8*)(vrow);
    short8 vf01 = *(const short8*)(vrow + 16);
    short8 vf10 = *(const short8*)(vrow + 32 * TT);
    short8 vf11 = *(const short8*)(vrow + 32 * TT + 16);

    f32x16 s;
#pragma unroll
    for (int r = 0; r < 16; ++r) s[r] = 0.f;
    s = __builtin_amdgcn_mfma_f32_32x32x16_bf16(k0, qf[0], s, 0, 0, 0);
    s = __builtin_amdgcn_mfma_f32_32x32x16_bf16(k1, qf[1], s, 0, 0, 0);
    s = __builtin_amdgcn_mfma_f32_32x32x16_bf16(k2, qf[2], s, 0, 0, 0);
    s = __builtin_amdgcn_mfma_f32_32x32x16_bf16(k3, qf[3], s, 0, 0, 0);

    // masks only on peeled steps (wave-uniform branches)
    float sv[16];
    if (kv == q0) {            // causal (global last step)
#pragma unroll
      for (int r = 0; r < 16; ++r) {
        int key = kv + (r & 3) + 8 * (r >> 2) + 4 * hi;
        sv[r] = (key <= q) ? s[r] : -1e30f;
      }
    } else if (q0 >= WIN && kv == kv_lo) {   // window edge (global first step)
#pragma unroll
      for (int r = 0; r < 16; ++r) {
        int key = kv + (r & 3) + 8 * (r >> 2) + 4 * hi;
        sv[r] = (key + WIN >= q) ? s[r] : -1e30f;
      }
    } else {
#pragma unroll
      for (int r = 0; r < 16; ++r) sv[r] = s[r];
    }

    float a0 = fmaxf(sv[0], sv[1]),   a1 = fmaxf(sv[2], sv[3]);
    float a2 = fmaxf(sv[4], sv[5]),   a3 = fmaxf(sv[6], sv[7]);
    float a4 = fmaxf(sv[8], sv[9]),   a5 = fmaxf(sv[10], sv[11]);
    float a6 = fmaxf(sv[12], sv[13]), a7 = fmaxf(sv[14], sv[15]);
    float b0 = fmaxf(a0, a1), b1 = fmaxf(a2, a3), b2 = fmaxf(a4, a5), b3 = fmaxf(a6, a7);
    float lm = fmaxf(fmaxf(b0, b1), fmaxf(b2, b3));
    lm = xmax32(lm);

    if (!__all(lm - mrun <= 8.f)) {
      float mnew = fmaxf(mrun, lm);
      float scf = __builtin_exp2f(mrun - mnew);
      mrun = mnew;
      lrun *= scf;
#pragma unroll
      for (int r = 0; r < 16; ++r) { o0[r] *= scf; o1[r] *= scf; }
    }

    float pv[16];
#pragma unroll
    for (int r = 0; r < 16; ++r) pv[r] = __builtin_exp2f(sv[r] - mrun);
    float c0 = (pv[0] + pv[1]) + (pv[2] + pv[3]);
    float c1 = (pv[4] + pv[5]) + (pv[6] + pv[7]);
    float c2 = (pv[8] + pv[9]) + (pv[10] + pv[11]);
    float c3 = (pv[12] + pv[13]) + (pv[14] + pv[15]);
    lrun += xsum32((c0 + c1) + (c2 + c3));

    unsigned w0 = cvt_pk_bf16(pv[0],  pv[1]),  w1 = cvt_pk_bf16(pv[2],  pv[3]);
    unsigned w2 = cvt_pk_bf16(pv[4],  pv[5]),  w3 = cvt_pk_bf16(pv[6],  pv[7]);
    unsigned w4 = cvt_pk_bf16(pv[8],  pv[9]),  w5 = cvt_pk_bf16(pv[10], pv[11]);
    unsigned w6 = cvt_pk_bf16(pv[12], pv[13]), w7 = cvt_pk_bf16(pv[14], pv[15]);
    auto s1 = __builtin_amdgcn_permlane32_swap(w0, w2, false, false);
    auto s2 = __builtin_amdgcn_permlane32_swap(w1, w3, false, false);
    auto s3 = __builtin_amdgcn_permlane32_swap(w4, w6, false, false);
    auto s4 = __builtin_amdgcn_permlane32_swap(w5, w7, false, false);
    union { unsigned u[4]; short8 s8; } pf0, pf1;
    pf0.u[0] = s1[0]; pf0.u[1] = s2[0]; pf0.u[2] = s1[1]; pf0.u[3] = s2[1];
    pf1.u[0] = s3[0]; pf1.u[1] = s4[0]; pf1.u[2] = s3[1]; pf1.u[3] = s4[1];

    o0 = __builtin_amdgcn_mfma_f32_32x32x16_bf16(vf00, pf0.s8, o0, 0, 0, 0);
    o1 = __builtin_amdgcn_mfma_f32_32x32x16_bf16(vf10, pf0.s8, o1, 0, 0, 0);
    o0 = __builtin_amdgcn_mfma_f32_32x32x16_bf16(vf01, pf1.s8, o0, 0, 0, 0);
    o1 = __builtin_amdgcn_mfma_f32_32x32x16_bf16(vf11, pf1.s8, o1, 0, 0, 0);
  }

  // ---- combine across the 4 waves ----
  if (hi == 0) { lds_m[wid][l31] = mrun; lds_l[wid][l31] = lrun; }
  __syncthreads();
  float m0 = lds_m[0][l31], m1 = lds_m[1][l31], m2 = lds_m[2][l31], m3 = lds_m[3][l31];
  float mstar = fmaxf(fmaxf(m0, m1), fmaxf(m2, m3));
  float myscale = __builtin_exp2f(mrun - mstar);
  if (wid != 0) {
#pragma unroll
    for (int r = 0; r < 16; ++r) {
      lds_O[wid - 1][lane][r]      = o0[r] * myscale;
      lds_O[wid - 1][lane][16 + r] = o1[r] * myscale;
    }
  }
  __syncthreads();
  if (wid == 0) {
    float lstar = __builtin_exp2f(m0 - mstar) * lds_l[0][l31]
                + __builtin_exp2f(m1 - mstar) * lds_l[1][l31]
                + __builtin_exp2f(m2 - mstar) * lds_l[2][l31]
                + __builtin_exp2f(m3 - mstar) * lds_l[3][l31];
    float gv = gate[((size_t)b * TT + q) * NHEADS + h];
    float inv = gv / lstar;
    float of0[16], of1[16];
#pragma unroll
    for (int r = 0; r < 16; ++r) {
      of0[r] = o0[r] * myscale + lds_O[0][lane][r]      + lds_O[1][lane][r]      + lds_O[2][lane][r];
      of1[r] = o1[r] * myscale + lds_O[0][lane][16 + r] + lds_O[1][lane][16 + r] + lds_O[2][lane][16 + r];
    }
    unsigned short* orow = attn_out + ((size_t)b * TT + q) * DIMM + h * HDIM;
#pragma unroll
    for (int a2 = 0; a2 < 4; ++a2) {
      int d0 = a2 * 8 + hi * 4;
      union { unsigned short s[4]; uint2 u; } x0, x1;
#pragma unroll
      for (int c = 0; c < 4; ++c) {
        x0.s[c] = f2b(of0[a2 * 4 + c] * inv);
        x1.s[c] = f2b(of1[a2 * 4 + c] * inv);
      }
      *(uint2*)(orow + d0) = x0.u;
      *(uint2*)(orow + 32 + d0) = x1.u;
    }
  }
}

// ---------------- workspace layout (bytes) ----------------
#define OFF_XB    ((size_t)0)
#define OFF_WQKV  ((size_t)8388608)
#define OFF_WO    ((size_t)14680064)
#define OFF_BCAT  ((size_t)16777216)
#define OFF_QKV   ((size_t)16793600)
#define OFF_QR    ((size_t)41959424)
#define OFF_KR    ((size_t)50348032)
#define OFF_VT    ((size_t)58736640)
#define OFF_ATTN  ((size_t)67125248)
#define OFF_GATE  ((size_t)75513856)

extern "C" void kernel_launch(void* const* d_in, const int* in_sizes, int n_in,
                              void* d_out, int out_size, void* d_ws, size_t ws_size,
                              hipStream_t stream) {
  const float* x    = (const float*)d_in[0];
  const float* Wq   = (const float*)d_in[1];
  const float* bq   = (const float*)d_in[2];
  const float* Wk   = (const float*)d_in[3];
  const float* bk   = (const float*)d_in[4];
  const float* Wv   = (const float*)d_in[5];
  const float* bv   = (const float*)d_in[6];
  const float* Wo   = (const float*)d_in[7];
  const float* bo   = (const float*)d_in[8];
  const float* Wg   = (const float*)d_in[9];
  const float* bg   = (const float*)d_in[10];
  const float* cosb = (const float*)d_in[11];
  const float* sinb = (const float*)d_in[12];
  float* out = (float*)d_out;
  char* ws = (char*)d_ws;

  unsigned short* xb    = (unsigned short*)(ws + OFF_XB);
  unsigned short* wqkv  = (unsigned short*)(ws + OFF_WQKV);
  unsigned short* wob   = (unsigned short*)(ws + OFF_WO);
  float*          bcat  = (float*)(ws + OFF_BCAT);
  unsigned short* qkv   = (unsigned short*)(ws + OFF_QKV);
  unsigned short* q_r   = (unsigned short*)(ws + OFF_QR);
  unsigned short* k_r   = (unsigned short*)(ws + OFF_KR);
  unsigned short* v_t   = (unsigned short*)(ws + OFF_VT);
  unsigned short* attn  = (unsigned short*)(ws + OFF_ATTN);
  float*          gateb = (float*)(ws + OFF_GATE);

  cvt_bf16_kernel<<<4096, 256, 0, stream>>>(x, xb, 4194304 / 4);
  cvt_bf16_kernel<<<1024, 256, 0, stream>>>(Wq, wqkv,            1048576 / 4);
  cvt_bf16_kernel<<<1024, 256, 0, stream>>>(Wk, wqkv + 1048576,  1048576 / 4);
  cvt_bf16_kernel<<<1024, 256, 0, stream>>>(Wv, wqkv + 2097152,  1048576 / 4);
  cvt_bf16_kernel<<<1024, 256, 0, stream>>>(Wo, wob,             1048576 / 4);
  bias_cat_kernel<<<12, 256, 0, stream>>>(bq, bk, bv, bcat);
  gate_kernel<<<256, 256, 0, stream>>>(x, Wg, bg, gateb);

  // fused QKV projection: [4096,1024] @ [3072,1024]^T
  gemm_bt<1><<<dim3(24, 32), 256, 0, stream>>>(xb, wqkv, bcat, qkv, MTOT, 3072, 1024);

  // RoPE (q scaled by 0.125*log2e) + V transpose
  rope_kernel<<<8192, 256, 0, stream>>>(qkv, cosb, sinb, q_r, k_r);
  vtrans_kernel<<<dim3(32, 32), 256, 0, stream>>>(qkv, v_t);

  // windowed causal flash attention + gate (4-way split-KV, LDS combine)
  attn_kernel<<<2048, 256, 0, stream>>>(q_r, k_r, v_t, gateb, attn);

  // output projection: [4096,1024] @ [1024,1024]^T + bo -> f32 out
  gemm_bt<0><<<dim3(8, 32), 256, 0, stream>>>(attn, wob, bo, out, MTOT, 1024, 1024);
}

// Round 7
// 127.714 us; speedup vs baseline: 2.2896x; 1.2506x over previous
//
#include <hip/hip_runtime.h>

#define DIMM 1024
#define NHEADS 16
#define HDIM 64
#define WIN 1024
#define GATEIN 20
#define BB 2
#define TT 2048
#define MTOT (BB*TT)   // 4096

typedef __attribute__((ext_vector_type(8))) short short8;
typedef __attribute__((ext_vector_type(4))) float f32x4;
typedef __attribute__((ext_vector_type(16))) float f32x16;
typedef const __attribute__((address_space(1))) void gvoid_t;
typedef __attribute__((address_space(3))) void lvoid_t;

__device__ __forceinline__ unsigned short f2b(float f) {
  union { float f; unsigned u; } c; c.f = f;
  unsigned u = c.u + 0x7fffu + ((c.u >> 16) & 1u);
  return (unsigned short)(u >> 16);
}
__device__ __forceinline__ float b2f(unsigned short s) {
  union { unsigned u; float f; } c; c.u = ((unsigned)s) << 16;
  return c.f;
}
__device__ __forceinline__ unsigned cvt_pk_bf16(float lo, float hi) {
  unsigned r;
  asm("v_cvt_pk_bf16_f32 %0, %1, %2" : "=v"(r) : "v"(lo), "v"(hi));
  return r;
}
// cross-half (lane ^ 32) reductions via permlane32_swap (VALU, no DS)
__device__ __forceinline__ float xmax32(float x) {
  union { float f; unsigned u; } c; c.f = x;
  auto pr = __builtin_amdgcn_permlane32_swap(c.u, c.u, false, false);
  union { unsigned u; float f; } a, b; a.u = pr[0]; b.u = pr[1];
  return fmaxf(a.f, b.f);
}
__device__ __forceinline__ float xsum32(float x) {
  union { float f; unsigned u; } c; c.f = x;
  auto pr = __builtin_amdgcn_permlane32_swap(c.u, c.u, false, false);
  union { unsigned u; float f; } a, b; a.u = pr[0]; b.u = pr[1];
  return a.f + b.f;
}

// ---------------- fused prep: bf16-cast x, Wq|Wk|Wv, Wo; concat biases ----------------
// segment boundaries all multiples of 256 -> wave-uniform branches
__global__ void prep_kernel(const float* __restrict__ x,  const float* __restrict__ Wq,
                            const float* __restrict__ Wk, const float* __restrict__ Wv,
                            const float* __restrict__ Wo, const float* __restrict__ bq,
                            const float* __restrict__ bk, const float* __restrict__ bv,
                            unsigned short* __restrict__ xb, unsigned short* __restrict__ wqkv,
                            unsigned short* __restrict__ wob, float* __restrict__ bcat) {
  int i = blockIdx.x * blockDim.x + threadIdx.x;
  const float* src; unsigned short* dst; int off;
  if (i < 1048576)      { src = x;  dst = xb;             off = i; }
  else if (i < 1310720) { src = Wq; dst = wqkv;           off = i - 1048576; }
  else if (i < 1572864) { src = Wk; dst = wqkv + 1048576; off = i - 1310720; }
  else if (i < 1835008) { src = Wv; dst = wqkv + 2097152; off = i - 1572864; }
  else if (i < 2097152) { src = Wo; dst = wob;            off = i - 1835008; }
  else {
    int j = i - 2097152;            // 0..767 : bias f32 copy
    if (j < 768) {
      const float* bsrc = (j < 256) ? bq : (j < 512) ? bk : bv;
      int bo = (j & 255) * 4;
      int db = (j < 256) ? 0 : (j < 512) ? 1024 : 2048;
      *(float4*)(bcat + db + bo) = *(const float4*)(bsrc + bo);
    }
    return;
  }
  float4 v = ((const float4*)src)[off];
  union { unsigned short s[4]; uint2 u; } o;
  o.s[0] = f2b(v.x); o.s[1] = f2b(v.y); o.s[2] = f2b(v.z); o.s[3] = f2b(v.w);
  *(uint2*)(dst + (size_t)off * 4) = o.u;
}

// ---------------- gate = sigmoid(x[:, :20] @ Wg^T + bg), [M][H] f32 ----------------
__global__ void gate_kernel(const float* __restrict__ x, const float* __restrict__ Wg,
                            const float* __restrict__ bg, float* __restrict__ gate) {
  int i = blockIdx.x * blockDim.x + threadIdx.x;   // M*H
  if (i >= MTOT * NHEADS) return;
  int h = i & 15;
  int m = i >> 4;
  const float* xr = x + (size_t)m * DIMM;
  const float* wr = Wg + h * GATEIN;
  float z = bg[h];
#pragma unroll
  for (int g = 0; g < GATEIN; ++g) z += xr[g] * wr[g];
  gate[i] = 1.f / (1.f + __expf(-z));
}

// ---------------- GEMM: C[M,N] = A[M,K] @ Bw[N,K]^T + bias, bf16 in, f32 acc ----------------
template<int OUTBF>
__global__ __launch_bounds__(256) void gemm_bt(const unsigned short* __restrict__ A,
                                               const unsigned short* __restrict__ Bw,
                                               const float* __restrict__ bias,
                                               void* __restrict__ Cout,
                                               int M, int N, int K) {
  __shared__ __align__(16) unsigned short As[128 * 32];
  __shared__ __align__(16) unsigned short Bs[128 * 32];
  const int tid = threadIdx.x;
  const int lane = tid & 63, wid = tid >> 6;
  const int g = lane >> 4, r16 = lane & 15;
  const int m0 = blockIdx.y * 128, n0 = blockIdx.x * 128;
  const int wr = (wid >> 1) * 64, wc = (wid & 1) * 64;
  const int wbase = wid * 64;

  f32x4 acc[4][4];
#pragma unroll
  for (int i = 0; i < 4; ++i)
#pragma unroll
    for (int j = 0; j < 4; ++j) acc[i][j] = (f32x4){0.f, 0.f, 0.f, 0.f};

  for (int k0 = 0; k0 < K; k0 += 32) {
#pragma unroll
    for (int j = 0; j < 2; ++j) {
      int sbase = j * 256 + wbase;
      int s = sbase + lane;
      const unsigned short* gA = A + (size_t)(m0 + (s >> 2)) * K + k0 + (s & 3) * 8;
      __builtin_amdgcn_global_load_lds((gvoid_t*)gA, (lvoid_t*)((char*)As + sbase * 16), 16, 0, 0);
      const unsigned short* gB = Bw + (size_t)(n0 + (s >> 2)) * K + k0 + (s & 3) * 8;
      __builtin_amdgcn_global_load_lds((gvoid_t*)gB, (lvoid_t*)((char*)Bs + sbase * 16), 16, 0, 0);
    }
    __syncthreads();
    short8 af[4], bf[4];
#pragma unroll
    for (int mf = 0; mf < 4; ++mf)
      af[mf] = *(const short8*)(As + (wr + mf * 16 + r16) * 32 + g * 8);
#pragma unroll
    for (int nf = 0; nf < 4; ++nf)
      bf[nf] = *(const short8*)(Bs + (wc + nf * 16 + r16) * 32 + g * 8);
#pragma unroll
    for (int mf = 0; mf < 4; ++mf)
#pragma unroll
      for (int nf = 0; nf < 4; ++nf)
        acc[mf][nf] = __builtin_amdgcn_mfma_f32_16x16x32_bf16(af[mf], bf[nf], acc[mf][nf], 0, 0, 0);
    __syncthreads();
  }
#pragma unroll
  for (int mf = 0; mf < 4; ++mf)
#pragma unroll
    for (int nf = 0; nf < 4; ++nf)
#pragma unroll
      for (int rr = 0; rr < 4; ++rr) {
        int m = m0 + wr + mf * 16 + g * 4 + rr;
        int n = n0 + wc + nf * 16 + r16;
        float v = acc[mf][nf][rr] + bias[n];
        if (OUTBF) ((unsigned short*)Cout)[(size_t)m * N + n] = f2b(v);
        else       ((float*)Cout)[(size_t)m * N + n] = v;
      }
}

// ---------------- RoPE + relayout ----------------
// q -> row-major [bh][t][64], scaled by 0.125*log2e (scores in log2 domain).
// k -> MFMA-fragment order [bh][kvtile][st(4)][hi(2)][l31(32)][j(8)]:
//      lane-coalesced attn loads (addr = kv*64 + st*512 + lane*8).
#define QSCALE (0.125f * 1.4426950408889634f)
__global__ void rope_kernel(const unsigned short* __restrict__ qkv,
                            const float* __restrict__ cosb, const float* __restrict__ sinb,
                            unsigned short* __restrict__ qr, unsigned short* __restrict__ kr) {
  int i = blockIdx.x * blockDim.x + threadIdx.x;   // M*H*32
  if (i >= MTOT * NHEADS * 32) return;
  int d = i & 31;
  int h = (i >> 5) & 15;
  int m = i >> 9;             // b*T + t
  int t = m & (TT - 1);
  int b = m >> 11;
  const unsigned short* row = qkv + (size_t)m * 3072;
  float c = cosb[t * 32 + d], s = sinb[t * 32 + d];
  float q1 = b2f(row[h * 64 + d]),        q2 = b2f(row[h * 64 + d + 32]);
  float k1 = b2f(row[1024 + h * 64 + d]), k2 = b2f(row[1024 + h * 64 + d + 32]);
  size_t base = (size_t)(b * NHEADS + h) * TT * HDIM;
  size_t oq = base + (size_t)t * HDIM + d;
  qr[oq]      = f2b((q1 * c - q2 * s) * QSCALE);
  qr[oq + 32] = f2b((q1 * s + q2 * c) * QSCALE);
  // k fragment layout: st = d>>4 (d<32 -> 0,1; d+32 -> +2), hi = (d>>3)&1, j = d&7
  size_t ok = base + (size_t)(t >> 5) * 2048 + (size_t)(d >> 4) * 512
            + (size_t)((d >> 3) & 1) * 256 + (size_t)(t & 31) * 8 + (d & 7);
  kr[ok]        = f2b(k1 * c - k2 * s);
  kr[ok + 1024] = f2b(k1 * s + k2 * c);   // st+2 -> +2*512
}

// ---------------- V transpose into fragment order ----------------
// vt layout [bh][kvtile][ (m*2+n)(4) ][hi(2)][l31(32)][j(8)]:
//   element V[t][d] at kvtile=t>>5, n=((t&31)>>4), hi=((t&31)>>3)&1, j=t&7, m=d>>5, l31=d&31
__global__ __launch_bounds__(256) void vtrans_kernel(const unsigned short* __restrict__ qkv,
                                                     unsigned short* __restrict__ vt) {
  __shared__ unsigned short tile[64][66];
  const int t0 = blockIdx.x * 64;
  const int bh = blockIdx.y;
  const int b = bh >> 4, h = bh & 15;
  const int tid = threadIdx.x;
  const int r = tid >> 2;
  const int c0 = (tid & 3) * 16;
  {
    const unsigned short* src = qkv + (size_t)(b * TT + t0 + r) * 3072 + 2048 + h * 64 + c0;
    short8 v0 = *(const short8*)src;
    short8 v1 = *(const short8*)(src + 8);
#pragma unroll
    for (int j = 0; j < 8; ++j) {
      tile[r][c0 + j] = (unsigned short)v0[j];
      tile[r][c0 + 8 + j] = (unsigned short)v1[j];
    }
  }
  __syncthreads();
  {
    const int d = tid >> 2;           // 0..63
    const int tc = (tid & 3) * 16;    // key chunk of 16
    short8 o0, o1;
#pragma unroll
    for (int j = 0; j < 8; ++j) {
      o0[j] = (short)tile[tc + j][d];       // keys tc..tc+7   (hi=0)
      o1[j] = (short)tile[tc + 8 + j][d];   // keys tc+8..tc+15 (hi=1)
    }
    int kt = (t0 + tc) >> 5;
    int n  = (tc >> 4) & 1;
    int m  = d >> 5, l31v = d & 31;
    size_t A0 = (size_t)bh * TT * HDIM + (size_t)kt * 2048
              + (size_t)(m * 2 + n) * 512 + (size_t)l31v * 8;
    *(short8*)(vt + A0)       = o0;
    *(short8*)(vt + A0 + 256) = o1;
  }
}

// ---------------- flash attention: 4-way split-KV, swapped QK^T (32x32) ----------------
// K/V in fragment order -> every per-step load is a coalesced 1KB wave load
// (R5 post-mortem: gathers made per-step chain ~5000cyc; this is the fix).
// Longest-first dispatch (qt descending) removes the low-occupancy tail.
__global__ __launch_bounds__(256) void attn_kernel(const unsigned short* __restrict__ qr,
                                                   const unsigned short* __restrict__ kr,
                                                   const unsigned short* __restrict__ vt,
                                                   const float* __restrict__ gate,
                                                   unsigned short* __restrict__ attn_out) {
  __shared__ float lds_m[4][32];
  __shared__ float lds_l[4][32];
  __shared__ float lds_O[3][64][33];
  const int tid = threadIdx.x;
  const int lane = tid & 63, wid = tid >> 6;
  const int l31 = lane & 31, hi = lane >> 5;

  // XCD swizzle + longest-first: per XCD, qt descends 63->0, 4 bh interleaved
  const int fid = blockIdx.x;
  const int idx = fid >> 3;                 // 0..255
  const int bh = (fid & 7) * 4 + (idx & 3);
  const int qt = 63 - (idx >> 2);
  const int q0 = qt * 32;
  const int b = bh >> 4, h = bh & 15;
  const unsigned short* kptr = kr + (size_t)bh * TT * HDIM;
  const unsigned short* vptr = vt + (size_t)bh * TT * HDIM;
  const int q = q0 + l31;                   // this lane's q row

  // Q B-frags (row-major; loaded once)
  short8 qf[4];
#pragma unroll
  for (int st = 0; st < 4; ++st)
    qf[st] = *(const short8*)(qr + (size_t)bh * TT * HDIM + (size_t)q * HDIM + st * 16 + hi * 8);

  f32x16 o0, o1;
#pragma unroll
  for (int r = 0; r < 16; ++r) { o0[r] = 0.f; o1[r] = 0.f; }
  float mrun = -1e30f, lrun = 0.f;

  int kv_lo = q0 - WIN;
  if (kv_lo < 0) kv_lo = 0;
  const int kv_hi = q0 + 32;

  // wave wid handles steps kv_lo + (wid + 4i)*32
  for (int kv = kv_lo + wid * 32; kv < kv_hi; kv += 128) {
    // fragment-order loads: coalesced (lane*8 shorts = 16B/lane, sequential)
    const unsigned short* kf = kptr + (size_t)kv * 64 + lane * 8;
    short8 k0 = *(const short8*)(kf);
    short8 k1 = *(const short8*)(kf + 512);
    short8 k2 = *(const short8*)(kf + 1024);
    short8 k3 = *(const short8*)(kf + 1536);
    const unsigned short* vf = vptr + (size_t)kv * 64 + lane * 8;
    short8 vf00 = *(const short8*)(vf);
    short8 vf01 = *(const short8*)(vf + 512);
    short8 vf10 = *(const short8*)(vf + 1024);
    short8 vf11 = *(const short8*)(vf + 1536);

    f32x16 s;
#pragma unroll
    for (int r = 0; r < 16; ++r) s[r] = 0.f;
    s = __builtin_amdgcn_mfma_f32_32x32x16_bf16(k0, qf[0], s, 0, 0, 0);
    s = __builtin_amdgcn_mfma_f32_32x32x16_bf16(k1, qf[1], s, 0, 0, 0);
    s = __builtin_amdgcn_mfma_f32_32x32x16_bf16(k2, qf[2], s, 0, 0, 0);
    s = __builtin_amdgcn_mfma_f32_32x32x16_bf16(k3, qf[3], s, 0, 0, 0);

    // masks only on peeled steps (wave-uniform branches)
    float sv[16];
    if (kv == q0) {            // causal (global last step)
#pragma unroll
      for (int r = 0; r < 16; ++r) {
        int key = kv + (r & 3) + 8 * (r >> 2) + 4 * hi;
        sv[r] = (key <= q) ? s[r] : -1e30f;
      }
    } else if (q0 >= WIN && kv == kv_lo) {   // window edge (global first step)
#pragma unroll
      for (int r = 0; r < 16; ++r) {
        int key = kv + (r & 3) + 8 * (r >> 2) + 4 * hi;
        sv[r] = (key + WIN >= q) ? s[r] : -1e30f;
      }
    } else {
#pragma unroll
      for (int r = 0; r < 16; ++r) sv[r] = s[r];
    }

    float a0 = fmaxf(sv[0], sv[1]),   a1 = fmaxf(sv[2], sv[3]);
    float a2 = fmaxf(sv[4], sv[5]),   a3 = fmaxf(sv[6], sv[7]);
    float a4 = fmaxf(sv[8], sv[9]),   a5 = fmaxf(sv[10], sv[11]);
    float a6 = fmaxf(sv[12], sv[13]), a7 = fmaxf(sv[14], sv[15]);
    float b0 = fmaxf(a0, a1), b1 = fmaxf(a2, a3), b2 = fmaxf(a4, a5), b3 = fmaxf(a6, a7);
    float lm = fmaxf(fmaxf(b0, b1), fmaxf(b2, b3));
    lm = xmax32(lm);

    if (!__all(lm - mrun <= 8.f)) {
      float mnew = fmaxf(mrun, lm);
      float scf = __builtin_exp2f(mrun - mnew);
      mrun = mnew;
      lrun *= scf;
#pragma unroll
      for (int r = 0; r < 16; ++r) { o0[r] *= scf; o1[r] *= scf; }
    }

    float pv[16];
#pragma unroll
    for (int r = 0; r < 16; ++r) pv[r] = __builtin_exp2f(sv[r] - mrun);
    float c0 = (pv[0] + pv[1]) + (pv[2] + pv[3]);
    float c1 = (pv[4] + pv[5]) + (pv[6] + pv[7]);
    float c2 = (pv[8] + pv[9]) + (pv[10] + pv[11]);
    float c3 = (pv[12] + pv[13]) + (pv[14] + pv[15]);
    lrun += xsum32((c0 + c1) + (c2 + c3));

    unsigned w0 = cvt_pk_bf16(pv[0],  pv[1]),  w1 = cvt_pk_bf16(pv[2],  pv[3]);
    unsigned w2 = cvt_pk_bf16(pv[4],  pv[5]),  w3 = cvt_pk_bf16(pv[6],  pv[7]);
    unsigned w4 = cvt_pk_bf16(pv[8],  pv[9]),  w5 = cvt_pk_bf16(pv[10], pv[11]);
    unsigned w6 = cvt_pk_bf16(pv[12], pv[13]), w7 = cvt_pk_bf16(pv[14], pv[15]);
    auto s1 = __builtin_amdgcn_permlane32_swap(w0, w2, false, false);
    auto s2 = __builtin_amdgcn_permlane32_swap(w1, w3, false, false);
    auto s3 = __builtin_amdgcn_permlane32_swap(w4, w6, false, false);
    auto s4 = __builtin_amdgcn_permlane32_swap(w5, w7, false, false);
    union { unsigned u[4]; short8 s8; } pf0, pf1;
    pf0.u[0] = s1[0]; pf0.u[1] = s2[0]; pf0.u[2] = s1[1]; pf0.u[3] = s2[1];
    pf1.u[0] = s3[0]; pf1.u[1] = s4[0]; pf1.u[2] = s3[1]; pf1.u[3] = s4[1];

    o0 = __builtin_amdgcn_mfma_f32_32x32x16_bf16(vf00, pf0.s8, o0, 0, 0, 0);
    o1 = __builtin_amdgcn_mfma_f32_32x32x16_bf16(vf10, pf0.s8, o1, 0, 0, 0);
    o0 = __builtin_amdgcn_mfma_f32_32x32x16_bf16(vf01, pf1.s8, o0, 0, 0, 0);
    o1 = __builtin_amdgcn_mfma_f32_32x32x16_bf16(vf11, pf1.s8, o1, 0, 0, 0);
  }

  // ---- combine across the 4 waves ----
  if (hi == 0) { lds_m[wid][l31] = mrun; lds_l[wid][l31] = lrun; }
  __syncthreads();
  float m0 = lds_m[0][l31], m1 = lds_m[1][l31], m2 = lds_m[2][l31], m3 = lds_m[3][l31];
  float mstar = fmaxf(fmaxf(m0, m1), fmaxf(m2, m3));
  float myscale = __builtin_exp2f(mrun - mstar);
  if (wid != 0) {
#pragma unroll
    for (int r = 0; r < 16; ++r) {
      lds_O[wid - 1][lane][r]      = o0[r] * myscale;
      lds_O[wid - 1][lane][16 + r] = o1[r] * myscale;
    }
  }
  __syncthreads();
  if (wid == 0) {
    float lstar = __builtin_exp2f(m0 - mstar) * lds_l[0][l31]
                + __builtin_exp2f(m1 - mstar) * lds_l[1][l31]
                + __builtin_exp2f(m2 - mstar) * lds_l[2][l31]
                + __builtin_exp2f(m3 - mstar) * lds_l[3][l31];
    float gv = gate[((size_t)b * TT + q) * NHEADS + h];
    float inv = gv / lstar;
    float of0[16], of1[16];
#pragma unroll
    for (int r = 0; r < 16; ++r) {
      of0[r] = o0[r] * myscale + lds_O[0][lane][r]      + lds_O[1][lane][r]      + lds_O[2][lane][r];
      of1[r] = o1[r] * myscale + lds_O[0][lane][16 + r] + lds_O[1][lane][16 + r] + lds_O[2][lane][16 + r];
    }
    unsigned short* orow = attn_out + ((size_t)b * TT + q) * DIMM + h * HDIM;
#pragma unroll
    for (int a2 = 0; a2 < 4; ++a2) {
      int d0 = a2 * 8 + hi * 4;
      union { unsigned short s[4]; uint2 u; } x0, x1;
#pragma unroll
      for (int c = 0; c < 4; ++c) {
        x0.s[c] = f2b(of0[a2 * 4 + c] * inv);
        x1.s[c] = f2b(of1[a2 * 4 + c] * inv);
      }
      *(uint2*)(orow + d0) = x0.u;
      *(uint2*)(orow + 32 + d0) = x1.u;
    }
  }
}

// ---------------- workspace layout (bytes) ----------------
#define OFF_XB    ((size_t)0)
#define OFF_WQKV  ((size_t)8388608)
#define OFF_WO    ((size_t)14680064)
#define OFF_BCAT  ((size_t)16777216)
#define OFF_QKV   ((size_t)16793600)
#define OFF_QR    ((size_t)41959424)
#define OFF_KR    ((size_t)50348032)
#define OFF_VT    ((size_t)58736640)
#define OFF_ATTN  ((size_t)67125248)
#define OFF_GATE  ((size_t)75513856)

extern "C" void kernel_launch(void* const* d_in, const int* in_sizes, int n_in,
                              void* d_out, int out_size, void* d_ws, size_t ws_size,
                              hipStream_t stream) {
  const float* x    = (const float*)d_in[0];
  const float* Wq   = (const float*)d_in[1];
  const float* bq   = (const float*)d_in[2];
  const float* Wk   = (const float*)d_in[3];
  const float* bk   = (const float*)d_in[4];
  const float* Wv   = (const float*)d_in[5];
  const float* bv   = (const float*)d_in[6];
  const float* Wo   = (const float*)d_in[7];
  const float* bo   = (const float*)d_in[8];
  const float* Wg   = (const float*)d_in[9];
  const float* bg   = (const float*)d_in[10];
  const float* cosb = (const float*)d_in[11];
  const float* sinb = (const float*)d_in[12];
  float* out = (float*)d_out;
  char* ws = (char*)d_ws;

  unsigned short* xb    = (unsigned short*)(ws + OFF_XB);
  unsigned short* wqkv  = (unsigned short*)(ws + OFF_WQKV);
  unsigned short* wob   = (unsigned short*)(ws + OFF_WO);
  float*          bcat  = (float*)(ws + OFF_BCAT);
  unsigned short* qkv   = (unsigned short*)(ws + OFF_QKV);
  unsigned short* q_r   = (unsigned short*)(ws + OFF_QR);
  unsigned short* k_r   = (unsigned short*)(ws + OFF_KR);
  unsigned short* v_t   = (unsigned short*)(ws + OFF_VT);
  unsigned short* attn  = (unsigned short*)(ws + OFF_ATTN);
  float*          gateb = (float*)(ws + OFF_GATE);

  // fused conversions + bias concat (was 6 launches)
  prep_kernel<<<8195, 256, 0, stream>>>(x, Wq, Wk, Wv, Wo, bq, bk, bv, xb, wqkv, wob, bcat);
  gate_kernel<<<256, 256, 0, stream>>>(x, Wg, bg, gateb);

  // fused QKV projection: [4096,1024] @ [3072,1024]^T
  gemm_bt<1><<<dim3(24, 32), 256, 0, stream>>>(xb, wqkv, bcat, qkv, MTOT, 3072, 1024);

  // RoPE (q row-major scaled; k fragment-order) + V transpose (fragment-order)
  rope_kernel<<<8192, 256, 0, stream>>>(qkv, cosb, sinb, q_r, k_r);
  vtrans_kernel<<<dim3(32, 32), 256, 0, stream>>>(qkv, v_t);

  // windowed causal flash attention + gate (coalesced frag loads, longest-first)
  attn_kernel<<<2048, 256, 0, stream>>>(q_r, k_r, v_t, gateb, attn);

  // output projection: [4096,1024] @ [1024,1024]^T + bo -> f32 out
  gemm_bt<0><<<dim3(8, 32), 256, 0, stream>>>(attn, wob, bo, out, MTOT, 1024, 1024);
}

// Round 8
// 119.706 us; speedup vs baseline: 2.4428x; 1.0669x over previous
//
#include <hip/hip_runtime.h>

#define DIMM 1024
#define NHEADS 16
#define HDIM 64
#define WIN 1024
#define GATEIN 20
#define BB 2
#define TT 2048
#define MTOT (BB*TT)   // 4096

typedef __attribute__((ext_vector_type(8))) short short8;
typedef __attribute__((ext_vector_type(4))) float f32x4;
typedef __attribute__((ext_vector_type(16))) float f32x16;
typedef const __attribute__((address_space(1))) void gvoid_t;
typedef __attribute__((address_space(3))) void lvoid_t;

__device__ __forceinline__ unsigned short f2b(float f) {
  union { float f; unsigned u; } c; c.f = f;
  unsigned u = c.u + 0x7fffu + ((c.u >> 16) & 1u);
  return (unsigned short)(u >> 16);
}
__device__ __forceinline__ float b2f(unsigned short s) {
  union { unsigned u; float f; } c; c.u = ((unsigned)s) << 16;
  return c.f;
}
__device__ __forceinline__ unsigned cvt_pk_bf16(float lo, float hi) {
  unsigned r;
  asm("v_cvt_pk_bf16_f32 %0, %1, %2" : "=v"(r) : "v"(lo), "v"(hi));
  return r;
}
// cross-half (lane ^ 32) reductions via permlane32_swap (VALU, no DS)
__device__ __forceinline__ float xmax32(float x) {
  union { float f; unsigned u; } c; c.f = x;
  auto pr = __builtin_amdgcn_permlane32_swap(c.u, c.u, false, false);
  union { unsigned u; float f; } a, b; a.u = pr[0]; b.u = pr[1];
  return fmaxf(a.f, b.f);
}
__device__ __forceinline__ float xsum32(float x) {
  union { float f; unsigned u; } c; c.f = x;
  auto pr = __builtin_amdgcn_permlane32_swap(c.u, c.u, false, false);
  union { unsigned u; float f; } a, b; a.u = pr[0]; b.u = pr[1];
  return a.f + b.f;
}

// ---------------- fused prep: bf16-cast x, Wq|Wk|Wv, Wo; concat biases ----------------
__global__ void prep_kernel(const float* __restrict__ x,  const float* __restrict__ Wq,
                            const float* __restrict__ Wk, const float* __restrict__ Wv,
                            const float* __restrict__ Wo, const float* __restrict__ bq,
                            const float* __restrict__ bk, const float* __restrict__ bv,
                            unsigned short* __restrict__ xb, unsigned short* __restrict__ wqkv,
                            unsigned short* __restrict__ wob, float* __restrict__ bcat) {
  int i = blockIdx.x * blockDim.x + threadIdx.x;
  const float* src; unsigned short* dst; int off;
  if (i < 1048576)      { src = x;  dst = xb;             off = i; }
  else if (i < 1310720) { src = Wq; dst = wqkv;           off = i - 1048576; }
  else if (i < 1572864) { src = Wk; dst = wqkv + 1048576; off = i - 1310720; }
  else if (i < 1835008) { src = Wv; dst = wqkv + 2097152; off = i - 1572864; }
  else if (i < 2097152) { src = Wo; dst = wob;            off = i - 1835008; }
  else {
    int j = i - 2097152;            // 0..767 : bias f32 copy
    if (j < 768) {
      const float* bsrc = (j < 256) ? bq : (j < 512) ? bk : bv;
      int bo = (j & 255) * 4;
      int db = (j < 256) ? 0 : (j < 512) ? 1024 : 2048;
      *(float4*)(bcat + db + bo) = *(const float4*)(bsrc + bo);
    }
    return;
  }
  float4 v = ((const float4*)src)[off];
  union { unsigned short s[4]; uint2 u; } o;
  o.s[0] = f2b(v.x); o.s[1] = f2b(v.y); o.s[2] = f2b(v.z); o.s[3] = f2b(v.w);
  *(uint2*)(dst + (size_t)off * 4) = o.u;
}

// ---------------- gate = sigmoid(x[:, :20] @ Wg^T + bg), [M][H] f32 ----------------
__global__ void gate_kernel(const float* __restrict__ x, const float* __restrict__ Wg,
                            const float* __restrict__ bg, float* __restrict__ gate) {
  int i = blockIdx.x * blockDim.x + threadIdx.x;   // M*H
  if (i >= MTOT * NHEADS) return;
  int h = i & 15;
  int m = i >> 4;
  const float* xr = x + (size_t)m * DIMM;
  const float* wr = Wg + h * GATEIN;
  float z = bg[h];
#pragma unroll
  for (int g = 0; g < GATEIN; ++g) z += xr[g] * wr[g];
  gate[i] = 1.f / (1.f + __expf(-z));
}

// ---------------- GEMM: C[M,N] = A[M,K] @ Bw[N,K]^T + bias ----------------
// Tile = (MF*32) x 128, 4 waves (2x2). LDS XOR-swizzle (T2, rule #21):
// linear global_load_lds dest + inverse-swizzled SOURCE slot + swizzled READ.
// Involution on 16B slots: l = s ^ ((s>>3)&3)  (kchunk bits ^ row bits 1-2).
// -> 16-row column reads hit all 8 bank-quads (was 8-way conflict, 3.1M ctr).
template<int MF, int OUTBF>
__global__ __launch_bounds__(256) void gemm_bt(const unsigned short* __restrict__ A,
                                               const unsigned short* __restrict__ Bw,
                                               const float* __restrict__ bias,
                                               void* __restrict__ Cout,
                                               int M, int N, int K) {
  __shared__ __align__(16) unsigned short As[MF * 32 * 32];
  __shared__ __align__(16) unsigned short Bs[128 * 32];
  const int tid = threadIdx.x;
  const int lane = tid & 63, wid = tid >> 6;
  const int g = lane >> 4, r16 = lane & 15;
  const int m0 = blockIdx.y * (MF * 32), n0 = blockIdx.x * 128;
  const int wr = (wid >> 1) * (MF * 16), wc = (wid & 1) * 64;
  const int wbase = wid * 64;

  // precomputed swizzled LDS read offsets (k-loop invariant), in shorts
  const unsigned short* paf[MF];
  const unsigned short* pbf[4];
#pragma unroll
  for (int mf = 0; mf < MF; ++mf) {
    int row = wr + mf * 16 + r16;
    paf[mf] = As + row * 32 + ((g ^ ((row >> 1) & 3)) * 8);
  }
#pragma unroll
  for (int nf = 0; nf < 4; ++nf) {
    int row = wc + nf * 16 + r16;
    pbf[nf] = Bs + row * 32 + ((g ^ ((row >> 1) & 3)) * 8);
  }

  f32x4 acc[MF][4];
#pragma unroll
  for (int i = 0; i < MF; ++i)
#pragma unroll
    for (int j = 0; j < 4; ++j) acc[i][j] = (f32x4){0.f, 0.f, 0.f, 0.f};

  for (int k0 = 0; k0 < K; k0 += 32) {
    // stage A: MF*128 slots; source slot = involution(physical slot)
#pragma unroll
    for (int j = 0; j < MF / 2; ++j) {
      int sbase = j * 256 + wbase;
      int s = sbase + lane;
      int l = s ^ ((s >> 3) & 3);
      const unsigned short* gA = A + (size_t)(m0 + (l >> 2)) * K + k0 + (l & 3) * 8;
      __builtin_amdgcn_global_load_lds((gvoid_t*)gA, (lvoid_t*)((char*)As + sbase * 16), 16, 0, 0);
    }
    // stage B: 512 slots
#pragma unroll
    for (int j = 0; j < 2; ++j) {
      int sbase = j * 256 + wbase;
      int s = sbase + lane;
      int l = s ^ ((s >> 3) & 3);
      const unsigned short* gB = Bw + (size_t)(n0 + (l >> 2)) * K + k0 + (l & 3) * 8;
      __builtin_amdgcn_global_load_lds((gvoid_t*)gB, (lvoid_t*)((char*)Bs + sbase * 16), 16, 0, 0);
    }
    __syncthreads();
    short8 af[MF], bf[4];
#pragma unroll
    for (int mf = 0; mf < MF; ++mf) af[mf] = *(const short8*)(paf[mf]);
#pragma unroll
    for (int nf = 0; nf < 4; ++nf)  bf[nf] = *(const short8*)(pbf[nf]);
#pragma unroll
    for (int mf = 0; mf < MF; ++mf)
#pragma unroll
      for (int nf = 0; nf < 4; ++nf)
        acc[mf][nf] = __builtin_amdgcn_mfma_f32_16x16x32_bf16(af[mf], bf[nf], acc[mf][nf], 0, 0, 0);
    __syncthreads();
  }
#pragma unroll
  for (int mf = 0; mf < MF; ++mf)
#pragma unroll
    for (int nf = 0; nf < 4; ++nf)
#pragma unroll
      for (int rr = 0; rr < 4; ++rr) {
        int m = m0 + wr + mf * 16 + g * 4 + rr;
        int n = n0 + wc + nf * 16 + r16;
        float v = acc[mf][nf][rr] + bias[n];
        if (OUTBF) ((unsigned short*)Cout)[(size_t)m * N + n] = f2b(v);
        else       ((float*)Cout)[(size_t)m * N + n] = v;
      }
}

// ---------------- RoPE + relayout ----------------
// q -> row-major [bh][t][64], scaled by 0.125*log2e (scores in log2 domain).
// k -> MFMA-fragment order [bh][kvtile][st(4)][hi(2)][l31(32)][j(8)]
#define QSCALE (0.125f * 1.4426950408889634f)
__global__ void rope_kernel(const unsigned short* __restrict__ qkv,
                            const float* __restrict__ cosb, const float* __restrict__ sinb,
                            unsigned short* __restrict__ qr, unsigned short* __restrict__ kr) {
  int i = blockIdx.x * blockDim.x + threadIdx.x;   // M*H*32
  if (i >= MTOT * NHEADS * 32) return;
  int d = i & 31;
  int h = (i >> 5) & 15;
  int m = i >> 9;             // b*T + t
  int t = m & (TT - 1);
  int b = m >> 11;
  const unsigned short* row = qkv + (size_t)m * 3072;
  float c = cosb[t * 32 + d], s = sinb[t * 32 + d];
  float q1 = b2f(row[h * 64 + d]),        q2 = b2f(row[h * 64 + d + 32]);
  float k1 = b2f(row[1024 + h * 64 + d]), k2 = b2f(row[1024 + h * 64 + d + 32]);
  size_t base = (size_t)(b * NHEADS + h) * TT * HDIM;
  size_t oq = base + (size_t)t * HDIM + d;
  qr[oq]      = f2b((q1 * c - q2 * s) * QSCALE);
  qr[oq + 32] = f2b((q1 * s + q2 * c) * QSCALE);
  size_t ok = base + (size_t)(t >> 5) * 2048 + (size_t)(d >> 4) * 512
            + (size_t)((d >> 3) & 1) * 256 + (size_t)(t & 31) * 8 + (d & 7);
  kr[ok]        = f2b(k1 * c - k2 * s);
  kr[ok + 1024] = f2b(k1 * s + k2 * c);   // st+2 -> +2*512
}

// ---------------- V transpose into fragment order ----------------
__global__ __launch_bounds__(256) void vtrans_kernel(const unsigned short* __restrict__ qkv,
                                                     unsigned short* __restrict__ vt) {
  __shared__ unsigned short tile[64][66];
  const int t0 = blockIdx.x * 64;
  const int bh = blockIdx.y;
  const int b = bh >> 4, h = bh & 15;
  const int tid = threadIdx.x;
  const int r = tid >> 2;
  const int c0 = (tid & 3) * 16;
  {
    const unsigned short* src = qkv + (size_t)(b * TT + t0 + r) * 3072 + 2048 + h * 64 + c0;
    short8 v0 = *(const short8*)src;
    short8 v1 = *(const short8*)(src + 8);
#pragma unroll
    for (int j = 0; j < 8; ++j) {
      tile[r][c0 + j] = (unsigned short)v0[j];
      tile[r][c0 + 8 + j] = (unsigned short)v1[j];
    }
  }
  __syncthreads();
  {
    const int d = tid >> 2;           // 0..63
    const int tc = (tid & 3) * 16;    // key chunk of 16
    short8 o0, o1;
#pragma unroll
    for (int j = 0; j < 8; ++j) {
      o0[j] = (short)tile[tc + j][d];
      o1[j] = (short)tile[tc + 8 + j][d];
    }
    int kt = (t0 + tc) >> 5;
    int n  = (tc >> 4) & 1;
    int m  = d >> 5, l31v = d & 31;
    size_t A0 = (size_t)bh * TT * HDIM + (size_t)kt * 2048
              + (size_t)(m * 2 + n) * 512 + (size_t)l31v * 8;
    *(short8*)(vt + A0)       = o0;
    *(short8*)(vt + A0 + 256) = o1;
  }
}

// ---------------- flash attention: 4-way split-KV, swapped QK^T (32x32) ----------------
__global__ __launch_bounds__(256) void attn_kernel(const unsigned short* __restrict__ qr,
                                                   const unsigned short* __restrict__ kr,
                                                   const unsigned short* __restrict__ vt,
                                                   const float* __restrict__ gate,
                                                   unsigned short* __restrict__ attn_out) {
  __shared__ float lds_m[4][32];
  __shared__ float lds_l[4][32];
  __shared__ float lds_O[3][64][33];
  const int tid = threadIdx.x;
  const int lane = tid & 63, wid = tid >> 6;
  const int l31 = lane & 31, hi = lane >> 5;

  const int fid = blockIdx.x;
  const int idx = fid >> 3;                 // 0..255
  const int bh = (fid & 7) * 4 + (idx & 3);
  const int qt = 63 - (idx >> 2);
  const int q0 = qt * 32;
  const int b = bh >> 4, h = bh & 15;
  const unsigned short* kptr = kr + (size_t)bh * TT * HDIM;
  const unsigned short* vptr = vt + (size_t)bh * TT * HDIM;
  const int q = q0 + l31;

  short8 qf[4];
#pragma unroll
  for (int st = 0; st < 4; ++st)
    qf[st] = *(const short8*)(qr + (size_t)bh * TT * HDIM + (size_t)q * HDIM + st * 16 + hi * 8);

  f32x16 o0, o1;
#pragma unroll
  for (int r = 0; r < 16; ++r) { o0[r] = 0.f; o1[r] = 0.f; }
  float mrun = -1e30f, lrun = 0.f;

  int kv_lo = q0 - WIN;
  if (kv_lo < 0) kv_lo = 0;
  const int kv_hi = q0 + 32;

  for (int kv = kv_lo + wid * 32; kv < kv_hi; kv += 128) {
    const unsigned short* kf = kptr + (size_t)kv * 64 + lane * 8;
    short8 k0 = *(const short8*)(kf);
    short8 k1 = *(const short8*)(kf + 512);
    short8 k2 = *(const short8*)(kf + 1024);
    short8 k3 = *(const short8*)(kf + 1536);
    const unsigned short* vf = vptr + (size_t)kv * 64 + lane * 8;
    short8 vf00 = *(const short8*)(vf);
    short8 vf01 = *(const short8*)(vf + 512);
    short8 vf10 = *(const short8*)(vf + 1024);
    short8 vf11 = *(const short8*)(vf + 1536);

    f32x16 s;
#pragma unroll
    for (int r = 0; r < 16; ++r) s[r] = 0.f;
    s = __builtin_amdgcn_mfma_f32_32x32x16_bf16(k0, qf[0], s, 0, 0, 0);
    s = __builtin_amdgcn_mfma_f32_32x32x16_bf16(k1, qf[1], s, 0, 0, 0);
    s = __builtin_amdgcn_mfma_f32_32x32x16_bf16(k2, qf[2], s, 0, 0, 0);
    s = __builtin_amdgcn_mfma_f32_32x32x16_bf16(k3, qf[3], s, 0, 0, 0);

    float sv[16];
    if (kv == q0) {
#pragma unroll
      for (int r = 0; r < 16; ++r) {
        int key = kv + (r & 3) + 8 * (r >> 2) + 4 * hi;
        sv[r] = (key <= q) ? s[r] : -1e30f;
      }
    } else if (q0 >= WIN && kv == kv_lo) {
#pragma unroll
      for (int r = 0; r < 16; ++r) {
        int key = kv + (r & 3) + 8 * (r >> 2) + 4 * hi;
        sv[r] = (key + WIN >= q) ? s[r] : -1e30f;
      }
    } else {
#pragma unroll
      for (int r = 0; r < 16; ++r) sv[r] = s[r];
    }

    float a0 = fmaxf(sv[0], sv[1]),   a1 = fmaxf(sv[2], sv[3]);
    float a2 = fmaxf(sv[4], sv[5]),   a3 = fmaxf(sv[6], sv[7]);
    float a4 = fmaxf(sv[8], sv[9]),   a5 = fmaxf(sv[10], sv[11]);
    float a6 = fmaxf(sv[12], sv[13]), a7 = fmaxf(sv[14], sv[15]);
    float b0 = fmaxf(a0, a1), b1 = fmaxf(a2, a3), b2 = fmaxf(a4, a5), b3 = fmaxf(a6, a7);
    float lm = fmaxf(fmaxf(b0, b1), fmaxf(b2, b3));
    lm = xmax32(lm);

    if (!__all(lm - mrun <= 8.f)) {
      float mnew = fmaxf(mrun, lm);
      float scf = __builtin_exp2f(mrun - mnew);
      mrun = mnew;
      lrun *= scf;
#pragma unroll
      for (int r = 0; r < 16; ++r) { o0[r] *= scf; o1[r] *= scf; }
    }

    float pv[16];
#pragma unroll
    for (int r = 0; r < 16; ++r) pv[r] = __builtin_exp2f(sv[r] - mrun);
    float c0 = (pv[0] + pv[1]) + (pv[2] + pv[3]);
    float c1 = (pv[4] + pv[5]) + (pv[6] + pv[7]);
    float c2 = (pv[8] + pv[9]) + (pv[10] + pv[11]);
    float c3 = (pv[12] + pv[13]) + (pv[14] + pv[15]);
    lrun += xsum32((c0 + c1) + (c2 + c3));

    unsigned w0 = cvt_pk_bf16(pv[0],  pv[1]),  w1 = cvt_pk_bf16(pv[2],  pv[3]);
    unsigned w2 = cvt_pk_bf16(pv[4],  pv[5]),  w3 = cvt_pk_bf16(pv[6],  pv[7]);
    unsigned w4 = cvt_pk_bf16(pv[8],  pv[9]),  w5 = cvt_pk_bf16(pv[10], pv[11]);
    unsigned w6 = cvt_pk_bf16(pv[12], pv[13]), w7 = cvt_pk_bf16(pv[14], pv[15]);
    auto s1 = __builtin_amdgcn_permlane32_swap(w0, w2, false, false);
    auto s2 = __builtin_amdgcn_permlane32_swap(w1, w3, false, false);
    auto s3 = __builtin_amdgcn_permlane32_swap(w4, w6, false, false);
    auto s4 = __builtin_amdgcn_permlane32_swap(w5, w7, false, false);
    union { unsigned u[4]; short8 s8; } pf0, pf1;
    pf0.u[0] = s1[0]; pf0.u[1] = s2[0]; pf0.u[2] = s1[1]; pf0.u[3] = s2[1];
    pf1.u[0] = s3[0]; pf1.u[1] = s4[0]; pf1.u[2] = s3[1]; pf1.u[3] = s4[1];

    o0 = __builtin_amdgcn_mfma_f32_32x32x16_bf16(vf00, pf0.s8, o0, 0, 0, 0);
    o1 = __builtin_amdgcn_mfma_f32_32x32x16_bf16(vf10, pf0.s8, o1, 0, 0, 0);
    o0 = __builtin_amdgcn_mfma_f32_32x32x16_bf16(vf01, pf1.s8, o0, 0, 0, 0);
    o1 = __builtin_amdgcn_mfma_f32_32x32x16_bf16(vf11, pf1.s8, o1, 0, 0, 0);
  }

  // ---- combine across the 4 waves ----
  if (hi == 0) { lds_m[wid][l31] = mrun; lds_l[wid][l31] = lrun; }
  __syncthreads();
  float m0 = lds_m[0][l31], m1 = lds_m[1][l31], m2 = lds_m[2][l31], m3 = lds_m[3][l31];
  float mstar = fmaxf(fmaxf(m0, m1), fmaxf(m2, m3));
  float myscale = __builtin_exp2f(mrun - mstar);
  if (wid != 0) {
#pragma unroll
    for (int r = 0; r < 16; ++r) {
      lds_O[wid - 1][lane][r]      = o0[r] * myscale;
      lds_O[wid - 1][lane][16 + r] = o1[r] * myscale;
    }
  }
  __syncthreads();
  if (wid == 0) {
    float lstar = __builtin_exp2f(m0 - mstar) * lds_l[0][l31]
                + __builtin_exp2f(m1 - mstar) * lds_l[1][l31]
                + __builtin_exp2f(m2 - mstar) * lds_l[2][l31]
                + __builtin_exp2f(m3 - mstar) * lds_l[3][l31];
    float gv = gate[((size_t)b * TT + q) * NHEADS + h];
    float inv = gv / lstar;
    float of0[16], of1[16];
#pragma unroll
    for (int r = 0; r < 16; ++r) {
      of0[r] = o0[r] * myscale + lds_O[0][lane][r]      + lds_O[1][lane][r]      + lds_O[2][lane][r];
      of1[r] = o1[r] * myscale + lds_O[0][lane][16 + r] + lds_O[1][lane][16 + r] + lds_O[2][lane][16 + r];
    }
    unsigned short* orow = attn_out + ((size_t)b * TT + q) * DIMM + h * HDIM;
#pragma unroll
    for (int a2 = 0; a2 < 4; ++a2) {
      int d0 = a2 * 8 + hi * 4;
      union { unsigned short s[4]; uint2 u; } x0, x1;
#pragma unroll
      for (int c = 0; c < 4; ++c) {
        x0.s[c] = f2b(of0[a2 * 4 + c] * inv);
        x1.s[c] = f2b(of1[a2 * 4 + c] * inv);
      }
      *(uint2*)(orow + d0) = x0.u;
      *(uint2*)(orow + 32 + d0) = x1.u;
    }
  }
}

// ---------------- workspace layout (bytes) ----------------
#define OFF_XB    ((size_t)0)
#define OFF_WQKV  ((size_t)8388608)
#define OFF_WO    ((size_t)14680064)
#define OFF_BCAT  ((size_t)16777216)
#define OFF_QKV   ((size_t)16793600)
#define OFF_QR    ((size_t)41959424)
#define OFF_KR    ((size_t)50348032)
#define OFF_VT    ((size_t)58736640)
#define OFF_ATTN  ((size_t)67125248)
#define OFF_GATE  ((size_t)75513856)

extern "C" void kernel_launch(void* const* d_in, const int* in_sizes, int n_in,
                              void* d_out, int out_size, void* d_ws, size_t ws_size,
                              hipStream_t stream) {
  const float* x    = (const float*)d_in[0];
  const float* Wq   = (const float*)d_in[1];
  const float* bq   = (const float*)d_in[2];
  const float* Wk   = (const float*)d_in[3];
  const float* bk   = (const float*)d_in[4];
  const float* Wv   = (const float*)d_in[5];
  const float* bv   = (const float*)d_in[6];
  const float* Wo   = (const float*)d_in[7];
  const float* bo   = (const float*)d_in[8];
  const float* Wg   = (const float*)d_in[9];
  const float* bg   = (const float*)d_in[10];
  const float* cosb = (const float*)d_in[11];
  const float* sinb = (const float*)d_in[12];
  float* out = (float*)d_out;
  char* ws = (char*)d_ws;

  unsigned short* xb    = (unsigned short*)(ws + OFF_XB);
  unsigned short* wqkv  = (unsigned short*)(ws + OFF_WQKV);
  unsigned short* wob   = (unsigned short*)(ws + OFF_WO);
  float*          bcat  = (float*)(ws + OFF_BCAT);
  unsigned short* qkv   = (unsigned short*)(ws + OFF_QKV);
  unsigned short* q_r   = (unsigned short*)(ws + OFF_QR);
  unsigned short* k_r   = (unsigned short*)(ws + OFF_KR);
  unsigned short* v_t   = (unsigned short*)(ws + OFF_VT);
  unsigned short* attn  = (unsigned short*)(ws + OFF_ATTN);
  float*          gateb = (float*)(ws + OFF_GATE);

  // fused conversions + bias concat
  prep_kernel<<<8195, 256, 0, stream>>>(x, Wq, Wk, Wv, Wo, bq, bk, bv, xb, wqkv, wob, bcat);
  gate_kernel<<<256, 256, 0, stream>>>(x, Wg, bg, gateb);

  // fused QKV projection: [4096,1024] @ [3072,1024]^T (128x128 tile, swizzled LDS)
  gemm_bt<4, 1><<<dim3(24, 32), 256, 0, stream>>>(xb, wqkv, bcat, qkv, MTOT, 3072, 1024);

  // RoPE (q row-major scaled; k fragment-order) + V transpose (fragment-order)
  rope_kernel<<<8192, 256, 0, stream>>>(qkv, cosb, sinb, q_r, k_r);
  vtrans_kernel<<<dim3(32, 32), 256, 0, stream>>>(qkv, v_t);

  // windowed causal flash attention + gate
  attn_kernel<<<2048, 256, 0, stream>>>(q_r, k_r, v_t, gateb, attn);

  // output projection: [4096,1024] @ [1024,1024]^T + bo (64x128 tile -> 512 blocks)
  gemm_bt<2, 0><<<dim3(8, 64), 256, 0, stream>>>(attn, wob, bo, out, MTOT, 1024, 1024);
}

// Round 9
// 114.578 us; speedup vs baseline: 2.5521x; 1.0448x over previous
//
#include <hip/hip_runtime.h>

#define DIMM 1024
#define NHEADS 16
#define HDIM 64
#define WIN 1024
#define GATEIN 20
#define BB 2
#define TT 2048
#define MTOT (BB*TT)   // 4096

typedef __attribute__((ext_vector_type(8))) short short8;
typedef __attribute__((ext_vector_type(4))) float f32x4;
typedef __attribute__((ext_vector_type(16))) float f32x16;
typedef const __attribute__((address_space(1))) void gvoid_t;
typedef __attribute__((address_space(3))) void lvoid_t;

__device__ __forceinline__ unsigned short f2b(float f) {
  union { float f; unsigned u; } c; c.f = f;
  unsigned u = c.u + 0x7fffu + ((c.u >> 16) & 1u);
  return (unsigned short)(u >> 16);
}
__device__ __forceinline__ float b2f(unsigned short s) {
  union { unsigned u; float f; } c; c.u = ((unsigned)s) << 16;
  return c.f;
}
__device__ __forceinline__ unsigned cvt_pk_bf16(float lo, float hi) {
  unsigned r;
  asm("v_cvt_pk_bf16_f32 %0, %1, %2" : "=v"(r) : "v"(lo), "v"(hi));
  return r;
}
__device__ __forceinline__ float max3f(float a, float b, float c) {
  return fmaxf(fmaxf(a, b), c);   // clang fuses to v_max3_f32
}
// cross-half (lane ^ 32) max via permlane32_swap (VALU, no DS)
__device__ __forceinline__ float xmax32(float x) {
  union { float f; unsigned u; } c; c.f = x;
  auto pr = __builtin_amdgcn_permlane32_swap(c.u, c.u, false, false);
  union { unsigned u; float f; } a, b; a.u = pr[0]; b.u = pr[1];
  return fmaxf(a.f, b.f);
}

// ---------------- fused prep: bf16-cast x, Wq|Wk|Wv, Wo; concat biases ----------------
__global__ void prep_kernel(const float* __restrict__ x,  const float* __restrict__ Wq,
                            const float* __restrict__ Wk, const float* __restrict__ Wv,
                            const float* __restrict__ Wo, const float* __restrict__ bq,
                            const float* __restrict__ bk, const float* __restrict__ bv,
                            unsigned short* __restrict__ xb, unsigned short* __restrict__ wqkv,
                            unsigned short* __restrict__ wob, float* __restrict__ bcat) {
  int i = blockIdx.x * blockDim.x + threadIdx.x;
  const float* src; unsigned short* dst; int off;
  if (i < 1048576)      { src = x;  dst = xb;             off = i; }
  else if (i < 1310720) { src = Wq; dst = wqkv;           off = i - 1048576; }
  else if (i < 1572864) { src = Wk; dst = wqkv + 1048576; off = i - 1310720; }
  else if (i < 1835008) { src = Wv; dst = wqkv + 2097152; off = i - 1572864; }
  else if (i < 2097152) { src = Wo; dst = wob;            off = i - 1835008; }
  else {
    int j = i - 2097152;            // 0..767 : bias f32 copy
    if (j < 768) {
      const float* bsrc = (j < 256) ? bq : (j < 512) ? bk : bv;
      int bo = (j & 255) * 4;
      int db = (j < 256) ? 0 : (j < 512) ? 1024 : 2048;
      *(float4*)(bcat + db + bo) = *(const float4*)(bsrc + bo);
    }
    return;
  }
  float4 v = ((const float4*)src)[off];
  union { unsigned short s[4]; uint2 u; } o;
  o.s[0] = f2b(v.x); o.s[1] = f2b(v.y); o.s[2] = f2b(v.z); o.s[3] = f2b(v.w);
  *(uint2*)(dst + (size_t)off * 4) = o.u;
}

// ---------------- gate = sigmoid(x[:, :20] @ Wg^T + bg), [M][H] f32 ----------------
__global__ void gate_kernel(const float* __restrict__ x, const float* __restrict__ Wg,
                            const float* __restrict__ bg, float* __restrict__ gate) {
  int i = blockIdx.x * blockDim.x + threadIdx.x;   // M*H
  if (i >= MTOT * NHEADS) return;
  int h = i & 15;
  int m = i >> 4;
  const float* xr = x + (size_t)m * DIMM;
  const float* wr = Wg + h * GATEIN;
  float z = bg[h];
#pragma unroll
  for (int g = 0; g < GATEIN; ++g) z += xr[g] * wr[g];
  gate[i] = 1.f / (1.f + __expf(-z));
}

// ---------------- GEMM: C[M,N] = A[M,K] @ Bw[N,K]^T + bias ----------------
// Tile = (MF*32) x 128, 4 waves. LDS XOR-swizzle (T2, rule #21).
template<int MF, int OUTBF>
__global__ __launch_bounds__(256) void gemm_bt(const unsigned short* __restrict__ A,
                                               const unsigned short* __restrict__ Bw,
                                               const float* __restrict__ bias,
                                               void* __restrict__ Cout,
                                               int M, int N, int K) {
  __shared__ __align__(16) unsigned short As[MF * 32 * 32];
  __shared__ __align__(16) unsigned short Bs[128 * 32];
  const int tid = threadIdx.x;
  const int lane = tid & 63, wid = tid >> 6;
  const int g = lane >> 4, r16 = lane & 15;
  const int m0 = blockIdx.y * (MF * 32), n0 = blockIdx.x * 128;
  const int wr = (wid >> 1) * (MF * 16), wc = (wid & 1) * 64;
  const int wbase = wid * 64;

  const unsigned short* paf[MF];
  const unsigned short* pbf[4];
#pragma unroll
  for (int mf = 0; mf < MF; ++mf) {
    int row = wr + mf * 16 + r16;
    paf[mf] = As + row * 32 + ((g ^ ((row >> 1) & 3)) * 8);
  }
#pragma unroll
  for (int nf = 0; nf < 4; ++nf) {
    int row = wc + nf * 16 + r16;
    pbf[nf] = Bs + row * 32 + ((g ^ ((row >> 1) & 3)) * 8);
  }

  f32x4 acc[MF][4];
#pragma unroll
  for (int i = 0; i < MF; ++i)
#pragma unroll
    for (int j = 0; j < 4; ++j) acc[i][j] = (f32x4){0.f, 0.f, 0.f, 0.f};

  for (int k0 = 0; k0 < K; k0 += 32) {
#pragma unroll
    for (int j = 0; j < MF / 2; ++j) {
      int sbase = j * 256 + wbase;
      int s = sbase + lane;
      int l = s ^ ((s >> 3) & 3);
      const unsigned short* gA = A + (size_t)(m0 + (l >> 2)) * K + k0 + (l & 3) * 8;
      __builtin_amdgcn_global_load_lds((gvoid_t*)gA, (lvoid_t*)((char*)As + sbase * 16), 16, 0, 0);
    }
#pragma unroll
    for (int j = 0; j < 2; ++j) {
      int sbase = j * 256 + wbase;
      int s = sbase + lane;
      int l = s ^ ((s >> 3) & 3);
      const unsigned short* gB = Bw + (size_t)(n0 + (l >> 2)) * K + k0 + (l & 3) * 8;
      __builtin_amdgcn_global_load_lds((gvoid_t*)gB, (lvoid_t*)((char*)Bs + sbase * 16), 16, 0, 0);
    }
    __syncthreads();
    short8 af[MF], bf[4];
#pragma unroll
    for (int mf = 0; mf < MF; ++mf) af[mf] = *(const short8*)(paf[mf]);
#pragma unroll
    for (int nf = 0; nf < 4; ++nf)  bf[nf] = *(const short8*)(pbf[nf]);
#pragma unroll
    for (int mf = 0; mf < MF; ++mf)
#pragma unroll
      for (int nf = 0; nf < 4; ++nf)
        acc[mf][nf] = __builtin_amdgcn_mfma_f32_16x16x32_bf16(af[mf], bf[nf], acc[mf][nf], 0, 0, 0);
    __syncthreads();
  }
#pragma unroll
  for (int mf = 0; mf < MF; ++mf)
#pragma unroll
    for (int nf = 0; nf < 4; ++nf)
#pragma unroll
      for (int rr = 0; rr < 4; ++rr) {
        int m = m0 + wr + mf * 16 + g * 4 + rr;
        int n = n0 + wc + nf * 16 + r16;
        float v = acc[mf][nf][rr] + bias[n];
        if (OUTBF) ((unsigned short*)Cout)[(size_t)m * N + n] = f2b(v);
        else       ((float*)Cout)[(size_t)m * N + n] = v;
      }
}

// ---------------- fused RoPE (q,k) + V transpose ----------------
// block = (ttile of 64, bh). q -> row-major [bh][t][64] scaled 0.125*log2e;
// k -> frag order [bh][kvtile][st(4)][hi(2)][l31(32)][j(8)]; v -> frag order via LDS.
#define QSCALE (0.125f * 1.4426950408889634f)
__global__ __launch_bounds__(256) void ropev_kernel(const unsigned short* __restrict__ qkv,
                                                    const float* __restrict__ cosb,
                                                    const float* __restrict__ sinb,
                                                    unsigned short* __restrict__ qr,
                                                    unsigned short* __restrict__ kr,
                                                    unsigned short* __restrict__ vt) {
  __shared__ unsigned short tile[64][66];
  const int t0 = blockIdx.x * 64;
  const int bh = blockIdx.y;
  const int b = bh >> 4, h = bh & 15;
  const int tid = threadIdx.x;
  const int tr = tid >> 2;          // 0..63 (row within tile)
  const int qd = tid & 3;           // quarter
  const int t = t0 + tr;
  const size_t base = (size_t)bh * TT * HDIM;
  const unsigned short* row = qkv + (size_t)(b * TT + t) * 3072 + h * 64;

  // ---- stage V tile into LDS (same mapping as old vtrans) ----
  {
    const unsigned short* vsrc = row + 2048 + qd * 16;
    short8 v0 = *(const short8*)vsrc;
    short8 v1 = *(const short8*)(vsrc + 8);
#pragma unroll
    for (int j = 0; j < 8; ++j) {
      tile[tr][qd * 16 + j]     = (unsigned short)v0[j];
      tile[tr][qd * 16 + 8 + j] = (unsigned short)v1[j];
    }
  }

  // ---- RoPE on q,k : this thread owns d = qd*8..+7 and +32 ----
  {
    const int d0 = qd * 8;
    short8 q1 = *(const short8*)(row + d0);
    short8 q2 = *(const short8*)(row + d0 + 32);
    short8 k1 = *(const short8*)(row + 1024 + d0);
    short8 k2 = *(const short8*)(row + 1024 + d0 + 32);
    float4 c0 = *(const float4*)(cosb + t * 32 + d0);
    float4 c1 = *(const float4*)(cosb + t * 32 + d0 + 4);
    float4 s0 = *(const float4*)(sinb + t * 32 + d0);
    float4 s1 = *(const float4*)(sinb + t * 32 + d0 + 4);
    float cc[8] = {c0.x, c0.y, c0.z, c0.w, c1.x, c1.y, c1.z, c1.w};
    float ss[8] = {s0.x, s0.y, s0.z, s0.w, s1.x, s1.y, s1.z, s1.w};
    short8 qo1, qo2, ko1, ko2;
#pragma unroll
    for (int j = 0; j < 8; ++j) {
      float a1 = b2f((unsigned short)q1[j]), a2 = b2f((unsigned short)q2[j]);
      float b1 = b2f((unsigned short)k1[j]), b2v = b2f((unsigned short)k2[j]);
      qo1[j] = (short)f2b((a1 * cc[j] - a2 * ss[j]) * QSCALE);
      qo2[j] = (short)f2b((a1 * ss[j] + a2 * cc[j]) * QSCALE);
      ko1[j] = (short)f2b(b1 * cc[j] - b2v * ss[j]);
      ko2[j] = (short)f2b(b1 * ss[j] + b2v * cc[j]);
    }
    *(short8*)(qr + base + (size_t)t * HDIM + d0)      = qo1;
    *(short8*)(qr + base + (size_t)t * HDIM + d0 + 32) = qo2;
    // k frag: st = d0>>4 = qd>>1, hi = qd&1
    size_t ok = base + (size_t)(t >> 5) * 2048 + (size_t)(qd >> 1) * 512
              + (size_t)(qd & 1) * 256 + (size_t)(t & 31) * 8;
    *(short8*)(kr + ok)        = ko1;
    *(short8*)(kr + ok + 1024) = ko2;   // d+32 -> st+2
  }
  __syncthreads();

  // ---- V out in frag order ----
  {
    const int d = tid >> 2;           // 0..63
    const int tc = (tid & 3) * 16;    // key chunk of 16
    short8 o0, o1;
#pragma unroll
    for (int j = 0; j < 8; ++j) {
      o0[j] = (short)tile[tc + j][d];
      o1[j] = (short)tile[tc + 8 + j][d];
    }
    int kt = (t0 + tc) >> 5;
    int n  = (tc >> 4) & 1;
    int m  = d >> 5, l31v = d & 31;
    size_t A0 = base + (size_t)kt * 2048 + (size_t)(m * 2 + n) * 512 + (size_t)l31v * 8;
    *(short8*)(vt + A0)       = o0;
    *(short8*)(vt + A0 + 256) = o1;
  }
}

// ---------------- flash attention: 4-way split-KV, swapped QK^T (32x32) ----------------
// VALU-trimmed step: SZERO-seeded S chain, in-place mask/exp, max3 tree,
// row-sum via ones-fragment MFMA (replaces 17-op add tree on critical path).
__global__ __launch_bounds__(256) void attn_kernel(const unsigned short* __restrict__ qr,
                                                   const unsigned short* __restrict__ kr,
                                                   const unsigned short* __restrict__ vt,
                                                   const float* __restrict__ gate,
                                                   unsigned short* __restrict__ attn_out) {
  __shared__ float lds_m[4][32];
  __shared__ float lds_l[4][32];
  __shared__ float lds_O[3][64][33];
  const int tid = threadIdx.x;
  const int lane = tid & 63, wid = tid >> 6;
  const int l31 = lane & 31, hi = lane >> 5;

  const int fid = blockIdx.x;
  const int idx = fid >> 3;                 // 0..255
  const int bh = (fid & 7) * 4 + (idx & 3);
  const int qt = 63 - (idx >> 2);
  const int q0 = qt * 32;
  const int b = bh >> 4, h = bh & 15;
  const unsigned short* kptr = kr + (size_t)bh * TT * HDIM;
  const unsigned short* vptr = vt + (size_t)bh * TT * HDIM;
  const int q = q0 + l31;

  short8 qf[4];
#pragma unroll
  for (int st = 0; st < 4; ++st)
    qf[st] = *(const short8*)(qr + (size_t)bh * TT * HDIM + (size_t)q * HDIM + st * 16 + hi * 8);

  f32x16 SZERO;
#pragma unroll
  for (int r = 0; r < 16; ++r) SZERO[r] = 0.f;
  short8 ONES;
#pragma unroll
  for (int j = 0; j < 8; ++j) ONES[j] = (short)0x3F80;   // bf16 1.0

  f32x16 o0 = SZERO, o1 = SZERO;
  float mrun = -1e30f, lrun = 0.f;

  int kv_lo = q0 - WIN;
  if (kv_lo < 0) kv_lo = 0;
  const int kv_hi = q0 + 32;

  for (int kv = kv_lo + wid * 32; kv < kv_hi; kv += 128) {
    const unsigned short* kf = kptr + (size_t)kv * 64 + lane * 8;
    short8 k0 = *(const short8*)(kf);
    short8 k1 = *(const short8*)(kf + 512);
    short8 k2 = *(const short8*)(kf + 1024);
    short8 k3 = *(const short8*)(kf + 1536);
    const unsigned short* vf = vptr + (size_t)kv * 64 + lane * 8;
    short8 vf00 = *(const short8*)(vf);
    short8 vf01 = *(const short8*)(vf + 512);
    short8 vf10 = *(const short8*)(vf + 1024);
    short8 vf11 = *(const short8*)(vf + 1536);

    f32x16 s;
    s = __builtin_amdgcn_mfma_f32_32x32x16_bf16(k0, qf[0], SZERO, 0, 0, 0);
    s = __builtin_amdgcn_mfma_f32_32x32x16_bf16(k1, qf[1], s, 0, 0, 0);
    s = __builtin_amdgcn_mfma_f32_32x32x16_bf16(k2, qf[2], s, 0, 0, 0);
    s = __builtin_amdgcn_mfma_f32_32x32x16_bf16(k3, qf[3], s, 0, 0, 0);

    // masks only on peeled steps (wave-uniform branches), in place
    if (kv == q0) {
#pragma unroll
      for (int r = 0; r < 16; ++r) {
        int key = kv + (r & 3) + 8 * (r >> 2) + 4 * hi;
        s[r] = (key <= q) ? s[r] : -1e30f;
      }
    } else if (q0 >= WIN && kv == kv_lo) {
#pragma unroll
      for (int r = 0; r < 16; ++r) {
        int key = kv + (r & 3) + 8 * (r >> 2) + 4 * hi;
        s[r] = (key + WIN >= q) ? s[r] : -1e30f;
      }
    }

    // row-max: max3 tree (depth 3) + cross-half swap
    float t0 = max3f(s[0],  s[1],  s[2]);
    float t1 = max3f(s[3],  s[4],  s[5]);
    float t2 = max3f(s[6],  s[7],  s[8]);
    float t3 = max3f(s[9],  s[10], s[11]);
    float t4 = max3f(s[12], s[13], s[14]);
    float lm = fmaxf(max3f(t0, t1, t2), max3f(t3, t4, s[15]));
    lm = xmax32(lm);

    if (!__all(lm - mrun <= 8.f)) {
      float mnew = fmaxf(mrun, lm);
      float scf = __builtin_exp2f(mrun - mnew);
      mrun = mnew;
      lrun *= scf;
#pragma unroll
      for (int r = 0; r < 16; ++r) { o0[r] *= scf; o1[r] *= scf; }
    }

    // P = exp2(s - mrun) in place; masked entries underflow to 0
#pragma unroll
    for (int r = 0; r < 16; ++r) s[r] = __builtin_exp2f(s[r] - mrun);

    // P -> bf16 B-frags: cvt_pk + permlane32_swap (T12)
    unsigned w0 = cvt_pk_bf16(s[0],  s[1]),  w1 = cvt_pk_bf16(s[2],  s[3]);
    unsigned w2 = cvt_pk_bf16(s[4],  s[5]),  w3 = cvt_pk_bf16(s[6],  s[7]);
    unsigned w4 = cvt_pk_bf16(s[8],  s[9]),  w5 = cvt_pk_bf16(s[10], s[11]);
    unsigned w6 = cvt_pk_bf16(s[12], s[13]), w7 = cvt_pk_bf16(s[14], s[15]);
    auto s1p = __builtin_amdgcn_permlane32_swap(w0, w2, false, false);
    auto s2p = __builtin_amdgcn_permlane32_swap(w1, w3, false, false);
    auto s3p = __builtin_amdgcn_permlane32_swap(w4, w6, false, false);
    auto s4p = __builtin_amdgcn_permlane32_swap(w5, w7, false, false);
    union { unsigned u[4]; short8 s8; } pf0, pf1;
    pf0.u[0] = s1p[0]; pf0.u[1] = s2p[0]; pf0.u[2] = s1p[1]; pf0.u[3] = s2p[1];
    pf1.u[0] = s3p[0]; pf1.u[1] = s4p[0]; pf1.u[2] = s3p[1]; pf1.u[3] = s4p[1];

    // row-sum via ones-fragment MFMA (all acc rows = sum over 32 keys)
    f32x16 ls;
    ls = __builtin_amdgcn_mfma_f32_32x32x16_bf16(ONES, pf0.s8, SZERO, 0, 0, 0);
    ls = __builtin_amdgcn_mfma_f32_32x32x16_bf16(ONES, pf1.s8, ls, 0, 0, 0);

    o0 = __builtin_amdgcn_mfma_f32_32x32x16_bf16(vf00, pf0.s8, o0, 0, 0, 0);
    o1 = __builtin_amdgcn_mfma_f32_32x32x16_bf16(vf10, pf0.s8, o1, 0, 0, 0);
    o0 = __builtin_amdgcn_mfma_f32_32x32x16_bf16(vf01, pf1.s8, o0, 0, 0, 0);
    o1 = __builtin_amdgcn_mfma_f32_32x32x16_bf16(vf11, pf1.s8, o1, 0, 0, 0);

    lrun += ls[0];
  }

  // ---- combine across the 4 waves ----
  if (hi == 0) { lds_m[wid][l31] = mrun; lds_l[wid][l31] = lrun; }
  __syncthreads();
  float m0 = lds_m[0][l31], m1 = lds_m[1][l31], m2 = lds_m[2][l31], m3 = lds_m[3][l31];
  float mstar = fmaxf(fmaxf(m0, m1), fmaxf(m2, m3));
  float myscale = __builtin_exp2f(mrun - mstar);
  if (wid != 0) {
#pragma unroll
    for (int r = 0; r < 16; ++r) {
      lds_O[wid - 1][lane][r]      = o0[r] * myscale;
      lds_O[wid - 1][lane][16 + r] = o1[r] * myscale;
    }
  }
  __syncthreads();
  if (wid == 0) {
    float lstar = __builtin_exp2f(m0 - mstar) * lds_l[0][l31]
                + __builtin_exp2f(m1 - mstar) * lds_l[1][l31]
                + __builtin_exp2f(m2 - mstar) * lds_l[2][l31]
                + __builtin_exp2f(m3 - mstar) * lds_l[3][l31];
    float gv = gate[((size_t)b * TT + q) * NHEADS + h];
    float inv = gv / lstar;
    float of0[16], of1[16];
#pragma unroll
    for (int r = 0; r < 16; ++r) {
      of0[r] = o0[r] * myscale + lds_O[0][lane][r]      + lds_O[1][lane][r]      + lds_O[2][lane][r];
      of1[r] = o1[r] * myscale + lds_O[0][lane][16 + r] + lds_O[1][lane][16 + r] + lds_O[2][lane][16 + r];
    }
    unsigned short* orow = attn_out + ((size_t)b * TT + q) * DIMM + h * HDIM;
#pragma unroll
    for (int a2 = 0; a2 < 4; ++a2) {
      int d0 = a2 * 8 + hi * 4;
      union { unsigned short s[4]; uint2 u; } x0, x1;
#pragma unroll
      for (int c = 0; c < 4; ++c) {
        x0.s[c] = f2b(of0[a2 * 4 + c] * inv);
        x1.s[c] = f2b(of1[a2 * 4 + c] * inv);
      }
      *(uint2*)(orow + d0) = x0.u;
      *(uint2*)(orow + 32 + d0) = x1.u;
    }
  }
}

// ---------------- workspace layout (bytes) ----------------
#define OFF_XB    ((size_t)0)
#define OFF_WQKV  ((size_t)8388608)
#define OFF_WO    ((size_t)14680064)
#define OFF_BCAT  ((size_t)16777216)
#define OFF_QKV   ((size_t)16793600)
#define OFF_QR    ((size_t)41959424)
#define OFF_KR    ((size_t)50348032)
#define OFF_VT    ((size_t)58736640)
#define OFF_ATTN  ((size_t)67125248)
#define OFF_GATE  ((size_t)75513856)

extern "C" void kernel_launch(void* const* d_in, const int* in_sizes, int n_in,
                              void* d_out, int out_size, void* d_ws, size_t ws_size,
                              hipStream_t stream) {
  const float* x    = (const float*)d_in[0];
  const float* Wq   = (const float*)d_in[1];
  const float* bq   = (const float*)d_in[2];
  const float* Wk   = (const float*)d_in[3];
  const float* bk   = (const float*)d_in[4];
  const float* Wv   = (const float*)d_in[5];
  const float* bv   = (const float*)d_in[6];
  const float* Wo   = (const float*)d_in[7];
  const float* bo   = (const float*)d_in[8];
  const float* Wg   = (const float*)d_in[9];
  const float* bg   = (const float*)d_in[10];
  const float* cosb = (const float*)d_in[11];
  const float* sinb = (const float*)d_in[12];
  float* out = (float*)d_out;
  char* ws = (char*)d_ws;

  unsigned short* xb    = (unsigned short*)(ws + OFF_XB);
  unsigned short* wqkv  = (unsigned short*)(ws + OFF_WQKV);
  unsigned short* wob   = (unsigned short*)(ws + OFF_WO);
  float*          bcat  = (float*)(ws + OFF_BCAT);
  unsigned short* qkv   = (unsigned short*)(ws + OFF_QKV);
  unsigned short* q_r   = (unsigned short*)(ws + OFF_QR);
  unsigned short* k_r   = (unsigned short*)(ws + OFF_KR);
  unsigned short* v_t   = (unsigned short*)(ws + OFF_VT);
  unsigned short* attn  = (unsigned short*)(ws + OFF_ATTN);
  float*          gateb = (float*)(ws + OFF_GATE);

  prep_kernel<<<8195, 256, 0, stream>>>(x, Wq, Wk, Wv, Wo, bq, bk, bv, xb, wqkv, wob, bcat);
  gate_kernel<<<256, 256, 0, stream>>>(x, Wg, bg, gateb);

  // fused QKV projection: [4096,1024] @ [3072,1024]^T (128x128 tile, swizzled LDS)
  gemm_bt<4, 1><<<dim3(24, 32), 256, 0, stream>>>(xb, wqkv, bcat, qkv, MTOT, 3072, 1024);

  // fused RoPE + V transpose
  ropev_kernel<<<dim3(32, 32), 256, 0, stream>>>(qkv, cosb, sinb, q_r, k_r, v_t);

  // windowed causal flash attention + gate
  attn_kernel<<<2048, 256, 0, stream>>>(q_r, k_r, v_t, gateb, attn);

  // output projection: [4096,1024] @ [1024,1024]^T + bo (64x128 tile -> 512 blocks)
  gemm_bt<2, 0><<<dim3(8, 64), 256, 0, stream>>>(attn, wob, bo, out, MTOT, 1024, 1024);
}

// Round 10
// 111.516 us; speedup vs baseline: 2.6222x; 1.0275x over previous
//
#include <hip/hip_runtime.h>

#define DIMM 1024
#define NHEADS 16
#define HDIM 64
#define WIN 1024
#define GATEIN 20
#define BB 2
#define TT 2048
#define MTOT (BB*TT)   // 4096

typedef __attribute__((ext_vector_type(8))) short short8;
typedef __attribute__((ext_vector_type(4))) float f32x4;
typedef __attribute__((ext_vector_type(16))) float f32x16;
typedef const __attribute__((address_space(1))) void gvoid_t;
typedef __attribute__((address_space(3))) void lvoid_t;

__device__ __forceinline__ unsigned short f2b(float f) {
  union { float f; unsigned u; } c; c.f = f;
  unsigned u = c.u + 0x7fffu + ((c.u >> 16) & 1u);
  return (unsigned short)(u >> 16);
}
__device__ __forceinline__ float b2f(unsigned short s) {
  union { unsigned u; float f; } c; c.u = ((unsigned)s) << 16;
  return c.f;
}
__device__ __forceinline__ unsigned cvt_pk_bf16(float lo, float hi) {
  unsigned r;
  asm("v_cvt_pk_bf16_f32 %0, %1, %2" : "=v"(r) : "v"(lo), "v"(hi));
  return r;
}
__device__ __forceinline__ float max3f(float a, float b, float c) {
  return fmaxf(fmaxf(a, b), c);   // clang fuses to v_max3_f32
}
// cross-half (lane ^ 32) max via permlane32_swap (VALU, no DS)
__device__ __forceinline__ float xmax32(float x) {
  union { float f; unsigned u; } c; c.f = x;
  auto pr = __builtin_amdgcn_permlane32_swap(c.u, c.u, false, false);
  union { unsigned u; float f; } a, b; a.u = pr[0]; b.u = pr[1];
  return fmaxf(a.f, b.f);
}

// ---------------- fused prep: bf16-cast x, Wq|Wk|Wv, Wo; concat biases ----------------
__global__ void prep_kernel(const float* __restrict__ x,  const float* __restrict__ Wq,
                            const float* __restrict__ Wk, const float* __restrict__ Wv,
                            const float* __restrict__ Wo, const float* __restrict__ bq,
                            const float* __restrict__ bk, const float* __restrict__ bv,
                            unsigned short* __restrict__ xb, unsigned short* __restrict__ wqkv,
                            unsigned short* __restrict__ wob, float* __restrict__ bcat) {
  int i = blockIdx.x * blockDim.x + threadIdx.x;
  const float* src; unsigned short* dst; int off;
  if (i < 1048576)      { src = x;  dst = xb;             off = i; }
  else if (i < 1310720) { src = Wq; dst = wqkv;           off = i - 1048576; }
  else if (i < 1572864) { src = Wk; dst = wqkv + 1048576; off = i - 1310720; }
  else if (i < 1835008) { src = Wv; dst = wqkv + 2097152; off = i - 1572864; }
  else if (i < 2097152) { src = Wo; dst = wob;            off = i - 1835008; }
  else {
    int j = i - 2097152;            // 0..767 : bias f32 copy
    if (j < 768) {
      const float* bsrc = (j < 256) ? bq : (j < 512) ? bk : bv;
      int bo = (j & 255) * 4;
      int db = (j < 256) ? 0 : (j < 512) ? 1024 : 2048;
      *(float4*)(bcat + db + bo) = *(const float4*)(bsrc + bo);
    }
    return;
  }
  float4 v = ((const float4*)src)[off];
  union { unsigned short s[4]; uint2 u; } o;
  o.s[0] = f2b(v.x); o.s[1] = f2b(v.y); o.s[2] = f2b(v.z); o.s[3] = f2b(v.w);
  *(uint2*)(dst + (size_t)off * 4) = o.u;
}

// ---------------- gate = sigmoid(x[:, :20] @ Wg^T + bg), [M][H] f32 ----------------
__global__ void gate_kernel(const float* __restrict__ x, const float* __restrict__ Wg,
                            const float* __restrict__ bg, float* __restrict__ gate) {
  int i = blockIdx.x * blockDim.x + threadIdx.x;   // M*H
  if (i >= MTOT * NHEADS) return;
  int h = i & 15;
  int m = i >> 4;
  const float* xr = x + (size_t)m * DIMM;
  const float* wr = Wg + h * GATEIN;
  float z = bg[h];
#pragma unroll
  for (int g = 0; g < GATEIN; ++g) z += xr[g] * wr[g];
  gate[i] = 1.f / (1.f + __expf(-z));
}

// ---------------- GEMM: C[M,N] = A[M,K] @ Bw[N,K]^T + bias ----------------
// Tile = (MF*32) x 128, 4 waves. LDS XOR-swizzle (T2) + double-buffered 2-phase:
// issue STAGE(t+1) BEFORE compute(t); single drain barrier per K-step, so the
// vmcnt(0) at __syncthreads lands after ~250cyc of MFMA (latency hidden).
template<int MF, int OUTBF>
__global__ __launch_bounds__(256) void gemm_bt(const unsigned short* __restrict__ A,
                                               const unsigned short* __restrict__ Bw,
                                               const float* __restrict__ bias,
                                               void* __restrict__ Cout,
                                               int M, int N, int K) {
  __shared__ __align__(16) unsigned short As[2][MF * 32 * 32];
  __shared__ __align__(16) unsigned short Bs[2][128 * 32];
  const int tid = threadIdx.x;
  const int lane = tid & 63, wid = tid >> 6;
  const int g = lane >> 4, r16 = lane & 15;
  const int m0 = blockIdx.y * (MF * 32), n0 = blockIdx.x * 128;
  const int wr = (wid >> 1) * (MF * 16), wc = (wid & 1) * 64;
  const int wbase = wid * 64;

  // swizzled LDS read offsets (k-loop invariant), in shorts, per buffer via +offset
  int oaf[MF], obf[4];
#pragma unroll
  for (int mf = 0; mf < MF; ++mf) {
    int row = wr + mf * 16 + r16;
    oaf[mf] = row * 32 + ((g ^ ((row >> 1) & 3)) * 8);
  }
#pragma unroll
  for (int nf = 0; nf < 4; ++nf) {
    int row = wc + nf * 16 + r16;
    obf[nf] = row * 32 + ((g ^ ((row >> 1) & 3)) * 8);
  }

  f32x4 acc[MF][4];
#pragma unroll
  for (int i = 0; i < MF; ++i)
#pragma unroll
    for (int j = 0; j < 4; ++j) acc[i][j] = (f32x4){0.f, 0.f, 0.f, 0.f};

  // per-lane inverse-swizzled global slot (source permutation == read permutation)
  auto stage = [&](int buf, int k0) {
#pragma unroll
    for (int j = 0; j < MF / 2; ++j) {
      int sbase = j * 256 + wbase;
      int s = sbase + lane;
      int l = s ^ ((s >> 3) & 3);
      const unsigned short* gA = A + (size_t)(m0 + (l >> 2)) * K + k0 + (l & 3) * 8;
      __builtin_amdgcn_global_load_lds((gvoid_t*)gA,
          (lvoid_t*)((char*)&As[buf][0] + sbase * 16), 16, 0, 0);
    }
#pragma unroll
    for (int j = 0; j < 2; ++j) {
      int sbase = j * 256 + wbase;
      int s = sbase + lane;
      int l = s ^ ((s >> 3) & 3);
      const unsigned short* gB = Bw + (size_t)(n0 + (l >> 2)) * K + k0 + (l & 3) * 8;
      __builtin_amdgcn_global_load_lds((gvoid_t*)gB,
          (lvoid_t*)((char*)&Bs[buf][0] + sbase * 16), 16, 0, 0);
    }
  };

  const int NT = K >> 5;
  stage(0, 0);
  __syncthreads();
  for (int t = 0; t < NT; ++t) {
    const int buf = t & 1;
    if (t + 1 < NT) stage(buf ^ 1, (t + 1) << 5);   // prefetch next tile
    short8 af[MF], bf[4];
#pragma unroll
    for (int mf = 0; mf < MF; ++mf) af[mf] = *(const short8*)(&As[buf][0] + oaf[mf]);
#pragma unroll
    for (int nf = 0; nf < 4; ++nf)  bf[nf] = *(const short8*)(&Bs[buf][0] + obf[nf]);
#pragma unroll
    for (int mf = 0; mf < MF; ++mf)
#pragma unroll
      for (int nf = 0; nf < 4; ++nf)
        acc[mf][nf] = __builtin_amdgcn_mfma_f32_16x16x32_bf16(af[mf], bf[nf], acc[mf][nf], 0, 0, 0);
    __syncthreads();   // drains prefetch (post-compute) + guards buf reuse
  }
#pragma unroll
  for (int mf = 0; mf < MF; ++mf)
#pragma unroll
    for (int nf = 0; nf < 4; ++nf)
#pragma unroll
      for (int rr = 0; rr < 4; ++rr) {
        int m = m0 + wr + mf * 16 + g * 4 + rr;
        int n = n0 + wc + nf * 16 + r16;
        float v = acc[mf][nf][rr] + bias[n];
        if (OUTBF) ((unsigned short*)Cout)[(size_t)m * N + n] = f2b(v);
        else       ((float*)Cout)[(size_t)m * N + n] = v;
      }
}

// ---------------- fused RoPE (q,k) + V transpose ----------------
#define QSCALE (0.125f * 1.4426950408889634f)
__global__ __launch_bounds__(256) void ropev_kernel(const unsigned short* __restrict__ qkv,
                                                    const float* __restrict__ cosb,
                                                    const float* __restrict__ sinb,
                                                    unsigned short* __restrict__ qr,
                                                    unsigned short* __restrict__ kr,
                                                    unsigned short* __restrict__ vt) {
  __shared__ unsigned short tile[64][66];
  const int t0 = blockIdx.x * 64;
  const int bh = blockIdx.y;
  const int b = bh >> 4, h = bh & 15;
  const int tid = threadIdx.x;
  const int tr = tid >> 2;          // 0..63 (row within tile)
  const int qd = tid & 3;           // quarter
  const int t = t0 + tr;
  const size_t base = (size_t)bh * TT * HDIM;
  const unsigned short* row = qkv + (size_t)(b * TT + t) * 3072 + h * 64;

  {
    const unsigned short* vsrc = row + 2048 + qd * 16;
    short8 v0 = *(const short8*)vsrc;
    short8 v1 = *(const short8*)(vsrc + 8);
#pragma unroll
    for (int j = 0; j < 8; ++j) {
      tile[tr][qd * 16 + j]     = (unsigned short)v0[j];
      tile[tr][qd * 16 + 8 + j] = (unsigned short)v1[j];
    }
  }

  {
    const int d0 = qd * 8;
    short8 q1 = *(const short8*)(row + d0);
    short8 q2 = *(const short8*)(row + d0 + 32);
    short8 k1 = *(const short8*)(row + 1024 + d0);
    short8 k2 = *(const short8*)(row + 1024 + d0 + 32);
    float4 c0 = *(const float4*)(cosb + t * 32 + d0);
    float4 c1 = *(const float4*)(cosb + t * 32 + d0 + 4);
    float4 s0 = *(const float4*)(sinb + t * 32 + d0);
    float4 s1 = *(const float4*)(sinb + t * 32 + d0 + 4);
    float cc[8] = {c0.x, c0.y, c0.z, c0.w, c1.x, c1.y, c1.z, c1.w};
    float ss[8] = {s0.x, s0.y, s0.z, s0.w, s1.x, s1.y, s1.z, s1.w};
    short8 qo1, qo2, ko1, ko2;
#pragma unroll
    for (int j = 0; j < 8; ++j) {
      float a1 = b2f((unsigned short)q1[j]), a2 = b2f((unsigned short)q2[j]);
      float b1 = b2f((unsigned short)k1[j]), b2v = b2f((unsigned short)k2[j]);
      qo1[j] = (short)f2b((a1 * cc[j] - a2 * ss[j]) * QSCALE);
      qo2[j] = (short)f2b((a1 * ss[j] + a2 * cc[j]) * QSCALE);
      ko1[j] = (short)f2b(b1 * cc[j] - b2v * ss[j]);
      ko2[j] = (short)f2b(b1 * ss[j] + b2v * cc[j]);
    }
    *(short8*)(qr + base + (size_t)t * HDIM + d0)      = qo1;
    *(short8*)(qr + base + (size_t)t * HDIM + d0 + 32) = qo2;
    size_t ok = base + (size_t)(t >> 5) * 2048 + (size_t)(qd >> 1) * 512
              + (size_t)(qd & 1) * 256 + (size_t)(t & 31) * 8;
    *(short8*)(kr + ok)        = ko1;
    *(short8*)(kr + ok + 1024) = ko2;   // d+32 -> st+2
  }
  __syncthreads();

  {
    const int d = tid >> 2;           // 0..63
    const int tc = (tid & 3) * 16;    // key chunk of 16
    short8 o0, o1;
#pragma unroll
    for (int j = 0; j < 8; ++j) {
      o0[j] = (short)tile[tc + j][d];
      o1[j] = (short)tile[tc + 8 + j][d];
    }
    int kt = (t0 + tc) >> 5;
    int n  = (tc >> 4) & 1;
    int m  = d >> 5, l31v = d & 31;
    size_t A0 = base + (size_t)kt * 2048 + (size_t)(m * 2 + n) * 512 + (size_t)l31v * 8;
    *(short8*)(vt + A0)       = o0;
    *(short8*)(vt + A0 + 256) = o1;
  }
}

// ---------------- flash attention: 4-way split-KV, swapped QK^T (32x32) ----------------
__global__ __launch_bounds__(256) void attn_kernel(const unsigned short* __restrict__ qr,
                                                   const unsigned short* __restrict__ kr,
                                                   const unsigned short* __restrict__ vt,
                                                   const float* __restrict__ gate,
                                                   unsigned short* __restrict__ attn_out) {
  __shared__ float lds_m[4][32];
  __shared__ float lds_l[4][32];
  __shared__ float lds_O[3][64][33];
  const int tid = threadIdx.x;
  const int lane = tid & 63, wid = tid >> 6;
  const int l31 = lane & 31, hi = lane >> 5;

  const int fid = blockIdx.x;
  const int idx = fid >> 3;                 // 0..255
  const int bh = (fid & 7) * 4 + (idx & 3);
  const int qt = 63 - (idx >> 2);
  const int q0 = qt * 32;
  const int b = bh >> 4, h = bh & 15;
  const unsigned short* kptr = kr + (size_t)bh * TT * HDIM;
  const unsigned short* vptr = vt + (size_t)bh * TT * HDIM;
  const int q = q0 + l31;

  short8 qf[4];
#pragma unroll
  for (int st = 0; st < 4; ++st)
    qf[st] = *(const short8*)(qr + (size_t)bh * TT * HDIM + (size_t)q * HDIM + st * 16 + hi * 8);

  f32x16 SZERO;
#pragma unroll
  for (int r = 0; r < 16; ++r) SZERO[r] = 0.f;
  short8 ONES;
#pragma unroll
  for (int j = 0; j < 8; ++j) ONES[j] = (short)0x3F80;   // bf16 1.0

  f32x16 o0 = SZERO, o1 = SZERO;
  float mrun = -1e30f, lrun = 0.f;

  int kv_lo = q0 - WIN;
  if (kv_lo < 0) kv_lo = 0;
  const int kv_hi = q0 + 32;

  for (int kv = kv_lo + wid * 32; kv < kv_hi; kv += 128) {
    const unsigned short* kf = kptr + (size_t)kv * 64 + lane * 8;
    short8 k0 = *(const short8*)(kf);
    short8 k1 = *(const short8*)(kf + 512);
    short8 k2 = *(const short8*)(kf + 1024);
    short8 k3 = *(const short8*)(kf + 1536);
    const unsigned short* vf = vptr + (size_t)kv * 64 + lane * 8;
    short8 vf00 = *(const short8*)(vf);
    short8 vf01 = *(const short8*)(vf + 512);
    short8 vf10 = *(const short8*)(vf + 1024);
    short8 vf11 = *(const short8*)(vf + 1536);

    f32x16 s;
    s = __builtin_amdgcn_mfma_f32_32x32x16_bf16(k0, qf[0], SZERO, 0, 0, 0);
    s = __builtin_amdgcn_mfma_f32_32x32x16_bf16(k1, qf[1], s, 0, 0, 0);
    s = __builtin_amdgcn_mfma_f32_32x32x16_bf16(k2, qf[2], s, 0, 0, 0);
    s = __builtin_amdgcn_mfma_f32_32x32x16_bf16(k3, qf[3], s, 0, 0, 0);

    if (kv == q0) {
#pragma unroll
      for (int r = 0; r < 16; ++r) {
        int key = kv + (r & 3) + 8 * (r >> 2) + 4 * hi;
        s[r] = (key <= q) ? s[r] : -1e30f;
      }
    } else if (q0 >= WIN && kv == kv_lo) {
#pragma unroll
      for (int r = 0; r < 16; ++r) {
        int key = kv + (r & 3) + 8 * (r >> 2) + 4 * hi;
        s[r] = (key + WIN >= q) ? s[r] : -1e30f;
      }
    }

    float t0 = max3f(s[0],  s[1],  s[2]);
    float t1 = max3f(s[3],  s[4],  s[5]);
    float t2 = max3f(s[6],  s[7],  s[8]);
    float t3 = max3f(s[9],  s[10], s[11]);
    float t4 = max3f(s[12], s[13], s[14]);
    float lm = fmaxf(max3f(t0, t1, t2), max3f(t3, t4, s[15]));
    lm = xmax32(lm);

    if (!__all(lm - mrun <= 8.f)) {
      float mnew = fmaxf(mrun, lm);
      float scf = __builtin_exp2f(mrun - mnew);
      mrun = mnew;
      lrun *= scf;
#pragma unroll
      for (int r = 0; r < 16; ++r) { o0[r] *= scf; o1[r] *= scf; }
    }

#pragma unroll
    for (int r = 0; r < 16; ++r) s[r] = __builtin_exp2f(s[r] - mrun);

    unsigned w0 = cvt_pk_bf16(s[0],  s[1]),  w1 = cvt_pk_bf16(s[2],  s[3]);
    unsigned w2 = cvt_pk_bf16(s[4],  s[5]),  w3 = cvt_pk_bf16(s[6],  s[7]);
    unsigned w4 = cvt_pk_bf16(s[8],  s[9]),  w5 = cvt_pk_bf16(s[10], s[11]);
    unsigned w6 = cvt_pk_bf16(s[12], s[13]), w7 = cvt_pk_bf16(s[14], s[15]);
    auto s1p = __builtin_amdgcn_permlane32_swap(w0, w2, false, false);
    auto s2p = __builtin_amdgcn_permlane32_swap(w1, w3, false, false);
    auto s3p = __builtin_amdgcn_permlane32_swap(w4, w6, false, false);
    auto s4p = __builtin_amdgcn_permlane32_swap(w5, w7, false, false);
    union { unsigned u[4]; short8 s8; } pf0, pf1;
    pf0.u[0] = s1p[0]; pf0.u[1] = s2p[0]; pf0.u[2] = s1p[1]; pf0.u[3] = s2p[1];
    pf1.u[0] = s3p[0]; pf1.u[1] = s4p[0]; pf1.u[2] = s3p[1]; pf1.u[3] = s4p[1];

    f32x16 ls;
    ls = __builtin_amdgcn_mfma_f32_32x32x16_bf16(ONES, pf0.s8, SZERO, 0, 0, 0);
    ls = __builtin_amdgcn_mfma_f32_32x32x16_bf16(ONES, pf1.s8, ls, 0, 0, 0);

    o0 = __builtin_amdgcn_mfma_f32_32x32x16_bf16(vf00, pf0.s8, o0, 0, 0, 0);
    o1 = __builtin_amdgcn_mfma_f32_32x32x16_bf16(vf10, pf0.s8, o1, 0, 0, 0);
    o0 = __builtin_amdgcn_mfma_f32_32x32x16_bf16(vf01, pf1.s8, o0, 0, 0, 0);
    o1 = __builtin_amdgcn_mfma_f32_32x32x16_bf16(vf11, pf1.s8, o1, 0, 0, 0);

    lrun += ls[0];
  }

  // ---- combine across the 4 waves ----
  if (hi == 0) { lds_m[wid][l31] = mrun; lds_l[wid][l31] = lrun; }
  __syncthreads();
  float m0 = lds_m[0][l31], m1 = lds_m[1][l31], m2 = lds_m[2][l31], m3 = lds_m[3][l31];
  float mstar = fmaxf(fmaxf(m0, m1), fmaxf(m2, m3));
  float myscale = __builtin_exp2f(mrun - mstar);
  if (wid != 0) {
#pragma unroll
    for (int r = 0; r < 16; ++r) {
      lds_O[wid - 1][lane][r]      = o0[r] * myscale;
      lds_O[wid - 1][lane][16 + r] = o1[r] * myscale;
    }
  }
  __syncthreads();
  if (wid == 0) {
    float lstar = __builtin_exp2f(m0 - mstar) * lds_l[0][l31]
                + __builtin_exp2f(m1 - mstar) * lds_l[1][l31]
                + __builtin_exp2f(m2 - mstar) * lds_l[2][l31]
                + __builtin_exp2f(m3 - mstar) * lds_l[3][l31];
    float gv = gate[((size_t)b * TT + q) * NHEADS + h];
    float inv = gv / lstar;
    float of0[16], of1[16];
#pragma unroll
    for (int r = 0; r < 16; ++r) {
      of0[r] = o0[r] * myscale + lds_O[0][lane][r]      + lds_O[1][lane][r]      + lds_O[2][lane][r];
      of1[r] = o1[r] * myscale + lds_O[0][lane][16 + r] + lds_O[1][lane][16 + r] + lds_O[2][lane][16 + r];
    }
    unsigned short* orow = attn_out + ((size_t)b * TT + q) * DIMM + h * HDIM;
#pragma unroll
    for (int a2 = 0; a2 < 4; ++a2) {
      int d0 = a2 * 8 + hi * 4;
      union { unsigned short s[4]; uint2 u; } x0, x1;
#pragma unroll
      for (int c = 0; c < 4; ++c) {
        x0.s[c] = f2b(of0[a2 * 4 + c] * inv);
        x1.s[c] = f2b(of1[a2 * 4 + c] * inv);
      }
      *(uint2*)(orow + d0) = x0.u;
      *(uint2*)(orow + 32 + d0) = x1.u;
    }
  }
}

// ---------------- workspace layout (bytes) ----------------
#define OFF_XB    ((size_t)0)
#define OFF_WQKV  ((size_t)8388608)
#define OFF_WO    ((size_t)14680064)
#define OFF_BCAT  ((size_t)16777216)
#define OFF_QKV   ((size_t)16793600)
#define OFF_QR    ((size_t)41959424)
#define OFF_KR    ((size_t)50348032)
#define OFF_VT    ((size_t)58736640)
#define OFF_ATTN  ((size_t)67125248)
#define OFF_GATE  ((size_t)75513856)

extern "C" void kernel_launch(void* const* d_in, const int* in_sizes, int n_in,
                              void* d_out, int out_size, void* d_ws, size_t ws_size,
                              hipStream_t stream) {
  const float* x    = (const float*)d_in[0];
  const float* Wq   = (const float*)d_in[1];
  const float* bq   = (const float*)d_in[2];
  const float* Wk   = (const float*)d_in[3];
  const float* bk   = (const float*)d_in[4];
  const float* Wv   = (const float*)d_in[5];
  const float* bv   = (const float*)d_in[6];
  const float* Wo   = (const float*)d_in[7];
  const float* bo   = (const float*)d_in[8];
  const float* Wg   = (const float*)d_in[9];
  const float* bg   = (const float*)d_in[10];
  const float* cosb = (const float*)d_in[11];
  const float* sinb = (const float*)d_in[12];
  float* out = (float*)d_out;
  char* ws = (char*)d_ws;

  unsigned short* xb    = (unsigned short*)(ws + OFF_XB);
  unsigned short* wqkv  = (unsigned short*)(ws + OFF_WQKV);
  unsigned short* wob   = (unsigned short*)(ws + OFF_WO);
  float*          bcat  = (float*)(ws + OFF_BCAT);
  unsigned short* qkv   = (unsigned short*)(ws + OFF_QKV);
  unsigned short* q_r   = (unsigned short*)(ws + OFF_QR);
  unsigned short* k_r   = (unsigned short*)(ws + OFF_KR);
  unsigned short* v_t   = (unsigned short*)(ws + OFF_VT);
  unsigned short* attn  = (unsigned short*)(ws + OFF_ATTN);
  float*          gateb = (float*)(ws + OFF_GATE);

  prep_kernel<<<8195, 256, 0, stream>>>(x, Wq, Wk, Wv, Wo, bq, bk, bv, xb, wqkv, wob, bcat);
  gate_kernel<<<256, 256, 0, stream>>>(x, Wg, bg, gateb);

  // fused QKV projection: [4096,1024] @ [3072,1024]^T (dbuf 2-phase, swizzled LDS)
  gemm_bt<4, 1><<<dim3(24, 32), 256, 0, stream>>>(xb, wqkv, bcat, qkv, MTOT, 3072, 1024);

  // fused RoPE + V transpose
  ropev_kernel<<<dim3(32, 32), 256, 0, stream>>>(qkv, cosb, sinb, q_r, k_r, v_t);

  // windowed causal flash attention + gate
  attn_kernel<<<2048, 256, 0, stream>>>(q_r, k_r, v_t, gateb, attn);

  // output projection: [4096,1024] @ [1024,1024]^T + bo (dbuf 2-phase)
  gemm_bt<2, 0><<<dim3(8, 64), 256, 0, stream>>>(attn, wob, bo, out, MTOT, 1024, 1024);
}